// Round 8
// baseline (379.026 us; speedup 1.0000x reference)
//
#include <hip/hip_runtime.h>
#include <hip/hip_bf16.h>
#include <cstddef>
#include <cstdint>

// ---------------- problem constants ----------------
#define MROWS 2048           // B8*L256
#define KBIG  16384          // DIN*CH32

typedef __attribute__((ext_vector_type(8))) short short8v;
typedef __attribute__((ext_vector_type(4))) short short4v;
typedef __attribute__((ext_vector_type(4))) float f32x4;
typedef unsigned int u32;

// ---------------- ws layout (float offsets) ----------------
static const size_t F_XT0  = 0;          // 2048*256
static const size_t F_SKIP = 524288;     // 2048*256
static const size_t F_XS   = 1048576;    // 2048*256
static const size_t F_XZ   = 1572864;    // 2048*1024
static const size_t F_XC   = 3670016;    // 2048*512
static const size_t F_XDBL = 4718592;    // 2048*80
static const size_t F_DT   = 4882432;    // 2048*512
static const size_t F_YG   = 5931008;    // 2048*512
static const size_t F_YM   = 6979584;    // 2048*256
static const size_t F_XS2  = 7503872;    // 2048*256
static const size_t F_CAT  = 8028160;    // 2048*512
static const size_t F_DEC  = 9076736;    // 2048*256 (ends 9601024)
static const size_t F_WMED = 9700000;    // med W tiles + conv W tiles
static const size_t F_WT0  = 10485760;   // lin0 split-bf16 tiles: 4194304 floats (ends 14680064)
static const size_t F_PART = 14680064;   // lin0 partial slabs 0-15 (16*2048*256, ends 23068672)
// lin0 partial slabs 16-31 live at float offset 0 (early chain region, free during lin0;
// ln32_k reads slab16 row m then writes XT0 row m -- same thread/address, safe).
static const size_t F_C1   = 10485760;   // conv ping-pong (aliases WT0+PART, dead by then)
static const size_t F_C2   = 0;          // aliases early chain (DEC @9076736 safe)
static const size_t F_C3   = 14680064;   // aliases PART (dead)
// total ws: 23068672 floats = 92,274,688 bytes

__device__ __forceinline__ float siluf(float v)     { return v / (1.f + __expf(-v)); }
__device__ __forceinline__ float softplusf(float v) { return v > 20.f ? v : log1pf(__expf(v)); }

__device__ __forceinline__ void split2(float v, short& h, short& l) {
  __hip_bfloat16 hb = __float2bfloat16(v);
  float hf = __bfloat162float(hb);
  __hip_bfloat16 lb = __float2bfloat16(v - hf);
  h = *(short*)&hb; l = *(short*)&lb;
}

__device__ __forceinline__ void glds16(const void* g, void* l) {
  __builtin_amdgcn_global_load_lds((const __attribute__((address_space(1))) u32*)g,
                                   (__attribute__((address_space(3))) u32*)l, 16, 0, 0);
}

#define MFMA3(acc, ah, al, bh, bl)                                            \
  acc = __builtin_amdgcn_mfma_f32_16x16x32_bf16(ah, bh, acc, 0, 0, 0);        \
  acc = __builtin_amdgcn_mfma_f32_16x16x32_bf16(al, bh, acc, 0, 0, 0);        \
  acc = __builtin_amdgcn_mfma_f32_16x16x32_bf16(ah, bl, acc, 0, 0, 0);

// ---------------- lin0 weight tiling (coalesced LDS-transpose) ----------------
// image: Wt[slot = (k'>>3)*256 + col][j = k'&7], k' = c*512+f, k = f*32+c.
__global__ __launch_bounds__(256) void tile_w_lin0(const float* __restrict__ w,
                                                   unsigned short* __restrict__ th,
                                                   unsigned short* __restrict__ tl) {
  __shared__ float ls[32 * 264];   // [col][k_l + k_l/32] pad-per-32
  int ct = blockIdx.x >> 6;        // 0..7  (col tile)
  int kt = blockIdx.x & 63;        // 0..63 (k tile)
  int c0 = ct << 5;
  int k0 = kt << 8;
  int tid = threadIdx.x;
  for (int u = tid; u < 2048; u += 256) {      // 2048 float4 units
    int col_l = u >> 6, f4i = u & 63;
    int k_l = f4i << 2;
    float4 v = *(const float4*)(w + (size_t)(c0 + col_l) * KBIG + k0 + k_l);
    float vv[4] = {v.x, v.y, v.z, v.w};
#pragma unroll
    for (int j = 0; j < 4; ++j) {
      int idx = k_l + j;
      ls[col_l * 264 + idx + (idx >> 5)] = vv[j];
    }
  }
  __syncthreads();
  for (int oi = tid; oi < 1024; oi += 256) {   // 32 cols x 32 c groups
    int col_l = oi & 31, c = oi >> 5;
    short8v h8, l8;
#pragma unroll
    for (int j = 0; j < 8; ++j) {
      float v = ls[col_l * 264 + j * 33 + c];
      short hh, ll; split2(v, hh, ll);
      h8[j] = hh; l8[j] = ll;
    }
    size_t slot = ((size_t)(c * 64 + kt)) * 256 + c0 + col_l;
    *(short8v*)(th + slot * 8) = h8;
    *(short8v*)(tl + slot * 8) = l8;
  }
}

// ---------------- generic med weight tiling: Wt[nt][s][kg(4)][col(128)][8]
__global__ __launch_bounds__(256) void tile_w_med(const float* __restrict__ w,
                                                  unsigned short* __restrict__ th,
                                                  unsigned short* __restrict__ tl,
                                                  int K, int nslots) {
  int slot = blockIdx.x * 256 + threadIdx.x;
  if (slot >= nslots) return;
  int NS = K >> 5;
  int col = slot & 127, kg = (slot >> 7) & 3, rest = slot >> 9;
  int s = rest % NS, nt = rest / NS;
  const float* src = w + (size_t)(nt * 128 + col) * K + (s << 5) + (kg << 3);
  short8v h8, l8;
#pragma unroll
  for (int j = 0; j < 8; ++j) {
    short hh, ll; split2(src[j], hh, ll);
    h8[j] = hh; l8[j] = ll;
  }
  *(short8v*)(th + (size_t)slot * 8) = h8;
  *(short8v*)(tl + (size_t)slot * 8) = l8;
}

// ---------------- conv weight tiling: k = dydx*16+ic (K=144 pad 160) ----------------
__global__ __launch_bounds__(256) void tile_w_conv(const float* __restrict__ w,
                                                   unsigned short* __restrict__ th,
                                                   unsigned short* __restrict__ tl) {
  int slot = blockIdx.x * 256 + threadIdx.x;   // 320 slots
  if (slot >= 320) return;
  int oc = slot & 15;
  int sfq = slot >> 4;           // s*4+fq, 0..19
  int s = sfq >> 2, fq = sfq & 3;
  short8v h8, l8;
#pragma unroll
  for (int j = 0; j < 8; ++j) {
    int k = s * 32 + fq * 8 + j;
    float v = 0.f;
    if (k < 144) {
      int dydx = k >> 4, ic = k & 15;
      v = w[oc * 144 + ic * 9 + dydx];
    }
    short hh, ll; split2(v, hh, ll);
    h8[j] = hh; l8[j] = ll;
  }
  *(short8v*)(th + (size_t)slot * 8) = h8;
  *(short8v*)(tl + (size_t)slot * 8) = l8;
}

// ---------------- lin0 MFMA GEMM: BM=256, BN=256(full), BK=32, split-K=32 ----------------
// grid = 8 mt x 32 z = 256 blocks = 1/CU. 512 threads = 8 waves (2m x 4n),
// wave tile 128x64. Each z == one input channel c. x read EXACTLY once;
// per-XCD weight set 2.1MB (L2-resident). A+B dbuf, 1 barrier/step, 16 steps.
__global__ __launch_bounds__(512, 2) void lin0_mfma(const float* __restrict__ x,
                                                    const unsigned short* __restrict__ wh,
                                                    const unsigned short* __restrict__ wl,
                                                    float* __restrict__ wsbase) {
  __shared__ short8v Ad[2][2][1024];   // [buf][h/l][kg*256 + row'] = 64KB
  __shared__ short8v Bd[2][2][1024];   // [buf][h/l][kg*256 + col]  = 64KB
  int bid = blockIdx.x;
  int mt = bid >> 5, z = bid & 31;     // bid%8 = z%8 -> 4 z-slabs per XCD
  int tid = threadIdx.x;
  int lane = tid & 63, wid = tid >> 6;
  int wm = wid >> 2, wn = wid & 3;
  int fi = lane & 15, fq = lane >> 4;
  // A staging: thread -> (row = tid>>1, k-half kh = tid&1): 16 floats each
  int arow = tid >> 1, kh = tid & 1;
  // mt == batch index (BM=256 == rows per batch), c == z
  const float* xrow = x + (size_t)mt * 4194304 + (size_t)z * 131072 + (size_t)arow * 512;
  // B staging roles: wave -> (kg = wid&3, h/l = wid>>2), 4 glds of 64 cols
  int skg = wid & 3, shl = wid >> 2;
  const unsigned short* wsrc = shl ? wl : wh;
  // frag read offsets
  int aoff[8], boff[4];
#pragma unroll
  for (int mi = 0; mi < 8; ++mi) {
    int row = wm * 128 + mi * 16 + fi;
    aoff[mi] = fq * 256 + (row ^ (fq << 2));
  }
#pragma unroll
  for (int ni = 0; ni < 4; ++ni) boff[ni] = fq * 256 + wn * 64 + ni * 16 + fi;

  f32x4 acc[8][4];
#pragma unroll
  for (int mi = 0; mi < 8; ++mi)
#pragma unroll
    for (int ni = 0; ni < 4; ++ni) acc[mi][ni] = (f32x4)(0.f);

  // ---- prologue: stage step 0 into buf 0 ----
  {
    int slotbase = ((z * 16 + 0) * 4 + skg) * 256;
#pragma unroll
    for (int q = 0; q < 4; ++q)
      glds16(wsrc + (size_t)(slotbase + q * 64 + lane) * 8,
             (void*)&Bd[0][shl][skg * 256 + q * 64]);
    int f0 = kh << 4;
    float vv[16];
#pragma unroll
    for (int j4 = 0; j4 < 4; ++j4) {
      float4 v = *(const float4*)(xrow + f0 + 4 * j4);
      vv[4 * j4] = v.x; vv[4 * j4 + 1] = v.y; vv[4 * j4 + 2] = v.z; vv[4 * j4 + 3] = v.w;
    }
#pragma unroll
    for (int jg = 0; jg < 2; ++jg) {
      short8v h8, l8;
#pragma unroll
      for (int j = 0; j < 8; ++j) { short hh, ll; split2(vv[jg * 8 + j], hh, ll); h8[j] = hh; l8[j] = ll; }
      int kg = (kh << 1) + jg;
      int idx = kg * 256 + (arow ^ (kg << 2));
      Ad[0][0][idx] = h8; Ad[0][1][idx] = l8;
    }
    __syncthreads();
  }

  for (int s = 0; s < 16; ++s) {
    int cb = s & 1, nb = cb ^ 1;
    bool more = s < 15;
    float vv[16];
    if (more) {
      int slotbase = ((z * 16 + s + 1) * 4 + skg) * 256;
#pragma unroll
      for (int q = 0; q < 4; ++q)
        glds16(wsrc + (size_t)(slotbase + q * 64 + lane) * 8,
               (void*)&Bd[nb][shl][skg * 256 + q * 64]);
      int f0 = ((s + 1) << 5) + (kh << 4);
#pragma unroll
      for (int j4 = 0; j4 < 4; ++j4) {
        float4 v = *(const float4*)(xrow + f0 + 4 * j4);
        vv[4 * j4] = v.x; vv[4 * j4 + 1] = v.y; vv[4 * j4 + 2] = v.z; vv[4 * j4 + 3] = v.w;
      }
    }
    // ---- compute on tile s (buf cb) ----
    short8v fah[8], fal[8];
#pragma unroll
    for (int mi = 0; mi < 8; ++mi) { fah[mi] = Ad[cb][0][aoff[mi]]; fal[mi] = Ad[cb][1][aoff[mi]]; }
#pragma unroll
    for (int ni = 0; ni < 4; ++ni) {
      short8v bh = Bd[cb][0][boff[ni]];
      short8v bl = Bd[cb][1][boff[ni]];
#pragma unroll
      for (int mi = 0; mi < 8; ++mi) { MFMA3(acc[mi][ni], fah[mi], fal[mi], bh, bl); }
    }
    if (more) {
#pragma unroll
      for (int jg = 0; jg < 2; ++jg) {
        short8v h8, l8;
#pragma unroll
        for (int j = 0; j < 8; ++j) { short hh, ll; split2(vv[jg * 8 + j], hh, ll); h8[j] = hh; l8[j] = ll; }
        int kg = (kh << 1) + jg;
        int idx = kg * 256 + (arow ^ (kg << 2));
        Ad[nb][0][idx] = h8; Ad[nb][1][idx] = l8;
      }
    }
    __syncthreads();   // nb writes visible + glds drained before next step
  }

  // ---- epilogue: write fp32 partials (slab z: 0-15 @ F_PART, 16-31 @ 0) ----
  size_t slabbase = (z < 16) ? (F_PART + (size_t)z * 524288) : ((size_t)(z - 16) * 524288);
  float* po = wsbase + slabbase + (size_t)mt * 65536;
#pragma unroll
  for (int mi = 0; mi < 8; ++mi)
#pragma unroll
    for (int ni = 0; ni < 4; ++ni) {
      int mloc = wm * 128 + mi * 16 + fq * 4;
      int n = wn * 64 + ni * 16 + fi;
#pragma unroll
      for (int r = 0; r < 4; ++r)
        po[(size_t)(mloc + r) * 256 + n] = acc[mi][ni][r];
    }
}

// ---------------- medium MFMA GEMM: BM=64, BN=128, BK=32 ----------------
template <int ACT, int HASBIAS>
__global__ __launch_bounds__(256, 2) void med_mfma(const float* __restrict__ A, int lda,
                                                   const unsigned short* __restrict__ wh,
                                                   const unsigned short* __restrict__ wl,
                                                   const float* __restrict__ bias,
                                                   float* __restrict__ out,
                                                   int K, int N) {
  __shared__ short8v Ahs[256], Als[256];
  __shared__ short8v Bd[2][2][512];
  int nt = blockIdx.x, mt = blockIdx.y;
  int NS = K >> 5;
  int tid = threadIdx.x;
  int lane = tid & 63, wid = tid >> 6;
  int fi = lane & 15, fq = lane >> 4;
  int arow = tid >> 2, akg = tid & 3;
  int awidx = akg * 64 + (arow ^ (akg << 2));
  int m0 = mt << 6;
  const float* ga = A + (size_t)(m0 + arow) * lda;
  size_t wtbase = (size_t)nt * NS;
  int aoff[4], boff[2];
#pragma unroll
  for (int mi = 0; mi < 4; ++mi) {
    int row = mi * 16 + fi;
    aoff[mi] = fq * 64 + (row ^ (fq << 2));
  }
#pragma unroll
  for (int ni = 0; ni < 2; ++ni) boff[ni] = fq * 128 + wid * 32 + ni * 16 + fi;

  f32x4 acc[4][2];
#pragma unroll
  for (int mi = 0; mi < 4; ++mi)
#pragma unroll
    for (int ni = 0; ni < 2; ++ni) acc[mi][ni] = (f32x4)(0.f);

  {
#pragma unroll
    for (int p = 0; p < 2; ++p) {
      int q = (wid << 1) + p;
      size_t gb = wtbase * 8192 + (size_t)q * 1024 + (size_t)lane * 16;
      glds16((const char*)wh + gb, (char*)&Bd[0][0][0] + q * 1024);
      glds16((const char*)wl + gb, (char*)&Bd[0][1][0] + q * 1024);
    }
    const float* gp = ga + (akg << 3);
    float4 v0 = *(const float4*)gp, v1 = *(const float4*)(gp + 4);
    float vv[8] = {v0.x, v0.y, v0.z, v0.w, v1.x, v1.y, v1.z, v1.w};
    short8v h8, l8;
#pragma unroll
    for (int j = 0; j < 8; ++j) { short hh, ll; split2(vv[j], hh, ll); h8[j] = hh; l8[j] = ll; }
    Ahs[awidx] = h8; Als[awidx] = l8;
    __syncthreads();
  }

  for (int s = 0; s < NS; ++s) {
    int cb = s & 1, nb = cb ^ 1;
    bool more = (s + 1) < NS;
    float4 v0, v1;
    if (more) {
#pragma unroll
      for (int p = 0; p < 2; ++p) {
        int q = (wid << 1) + p;
        size_t gb = (wtbase + s + 1) * 8192 + (size_t)q * 1024 + (size_t)lane * 16;
        glds16((const char*)wh + gb, (char*)&Bd[nb][0][0] + q * 1024);
        glds16((const char*)wl + gb, (char*)&Bd[nb][1][0] + q * 1024);
      }
      const float* gp = ga + ((s + 1) << 5) + (akg << 3);
      v0 = *(const float4*)gp; v1 = *(const float4*)(gp + 4);
    }
    short8v fah[4], fal[4];
#pragma unroll
    for (int mi = 0; mi < 4; ++mi) { fah[mi] = Ahs[aoff[mi]]; fal[mi] = Als[aoff[mi]]; }
#pragma unroll
    for (int ni = 0; ni < 2; ++ni) {
      short8v bh = Bd[cb][0][boff[ni]];
      short8v bl = Bd[cb][1][boff[ni]];
#pragma unroll
      for (int mi = 0; mi < 4; ++mi) { MFMA3(acc[mi][ni], fah[mi], fal[mi], bh, bl); }
    }
    __syncthreads();
    if (more) {
      float vv[8] = {v0.x, v0.y, v0.z, v0.w, v1.x, v1.y, v1.z, v1.w};
      short8v h8, l8;
#pragma unroll
      for (int j = 0; j < 8; ++j) { short hh, ll; split2(vv[j], hh, ll); h8[j] = hh; l8[j] = ll; }
      Ahs[awidx] = h8; Als[awidx] = l8;
    }
    __syncthreads();
  }

#pragma unroll
  for (int mi = 0; mi < 4; ++mi)
#pragma unroll
    for (int ni = 0; ni < 2; ++ni) {
      int n = (nt << 7) + wid * 32 + ni * 16 + fi;
      float bv = HASBIAS ? bias[n] : 0.f;
#pragma unroll
      for (int r = 0; r < 4; ++r) {
        int m = m0 + mi * 16 + fq * 4 + r;
        float v = acc[mi][ni][r] + bv;
        if (ACT == 1) v = fmaxf(v, 0.f);
        out[(size_t)m * N + n] = v;
      }
    }
}

// ---------------- sum 32 partials + bias -> relu -> LayerNorm (N=256) ----------------
__global__ __launch_bounds__(256) void ln32_k(const float* part_a, const float* part_b,
                                              const float* __restrict__ bias,
                                              const float* __restrict__ g,
                                              const float* __restrict__ bb,
                                              float* out) {
  int m = blockIdx.x, t = threadIdx.x;
  float s = bias[t];
  for (int z = 0; z < 16; ++z) s += part_a[((size_t)z * MROWS + m) * 256 + t];
  for (int z = 0; z < 16; ++z) s += part_b[((size_t)z * MROWS + m) * 256 + t];
  float v = fmaxf(s, 0.f);
  float sum = v, sq = v * v;
#pragma unroll
  for (int o = 1; o < 64; o <<= 1) { sum += __shfl_xor(sum, o); sq += __shfl_xor(sq, o); }
  __shared__ float s1[4], s2[4];
  int w = t >> 6;
  if ((t & 63) == 0) { s1[w] = sum; s2[w] = sq; }
  __syncthreads();
  sum = s1[0] + s1[1] + s1[2] + s1[3];
  sq  = s2[0] + s2[1] + s2[2] + s2[3];
  float mu  = sum * (1.f / 256.f);
  float var = sq * (1.f / 256.f) - mu * mu;
  out[(size_t)m * 256 + t] = (v - mu) * rsqrtf(var + 1e-5f) * g[t] + bb[t];
}

// ---------------- sum partials + bias -> relu -> LayerNorm (N=256) ----------------
__global__ __launch_bounds__(256) void ln_k(const float* __restrict__ part, int npart,
                                            const float* __restrict__ bias,
                                            const float* __restrict__ g,
                                            const float* __restrict__ bb,
                                            float* __restrict__ out) {
  int m = blockIdx.x, t = threadIdx.x;
  float s = bias[t];
  for (int z = 0; z < npart; ++z) s += part[((size_t)z * MROWS + m) * 256 + t];
  float v = fmaxf(s, 0.f);
  float sum = v, sq = v * v;
#pragma unroll
  for (int o = 1; o < 64; o <<= 1) { sum += __shfl_xor(sum, o); sq += __shfl_xor(sq, o); }
  __shared__ float s1[4], s2[4];
  int w = t >> 6;
  if ((t & 63) == 0) { s1[w] = sum; s2[w] = sq; }
  __syncthreads();
  sum = s1[0] + s1[1] + s1[2] + s1[3];
  sq  = s2[0] + s2[1] + s2[2] + s2[3];
  float mu  = sum * (1.f / 256.f);
  float var = sq * (1.f / 256.f) - mu * mu;
  out[(size_t)m * 256 + t] = (v - mu) * rsqrtf(var + 1e-5f) * g[t] + bb[t];
}

// ---------------- generic fp32 GEMM (kept for xproj N=80, dt K=16) ----------------
template <int RM, int ACT, int HASBIAS>
__global__ __launch_bounds__(256) void gemm_k(const float* __restrict__ A, int lda,
                                              const float* __restrict__ W,
                                              const float* __restrict__ bias,
                                              float* __restrict__ out,
                                              int M, int N, int K) {
  const int BM = RM * 16;
  __shared__ __align__(16) float As[16][RM * 16 + 4];
  __shared__ __align__(16) float Ws[16][68];
  int n0 = blockIdx.x << 6;
  int m0 = blockIdx.y * BM;
  int tid = threadIdx.x;
  int tx = tid & 15, ty = tid >> 4;
  float acc[RM][4];
#pragma unroll
  for (int r = 0; r < RM; ++r)
#pragma unroll
    for (int j = 0; j < 4; ++j) acc[r][j] = 0.f;

  for (int k0 = 0; k0 < K; k0 += 16) {
    __syncthreads();
    for (int i = tid; i < BM * 16; i += 256) {
      int r = i >> 4, kk = i & 15;
      As[kk][r] = A[(size_t)(m0 + r) * lda + k0 + kk];
    }
    for (int i = tid; i < 64 * 16; i += 256) {
      int r = i >> 4, kk = i & 15;
      int n = n0 + r;
      Ws[kk][r] = (n < N) ? W[(size_t)n * K + k0 + kk] : 0.f;
    }
    __syncthreads();
#pragma unroll
    for (int kk = 0; kk < 16; ++kk) {
      float4 wv = *(const float4*)&Ws[kk][tx << 2];
#pragma unroll
      for (int r = 0; r < RM; ++r) {
        float a = As[kk][ty * RM + r];
        acc[r][0] = fmaf(a, wv.x, acc[r][0]);
        acc[r][1] = fmaf(a, wv.y, acc[r][1]);
        acc[r][2] = fmaf(a, wv.z, acc[r][2]);
        acc[r][3] = fmaf(a, wv.w, acc[r][3]);
      }
    }
  }
#pragma unroll
  for (int r = 0; r < RM; ++r) {
    int m = m0 + ty * RM + r;
#pragma unroll
    for (int j = 0; j < 4; ++j) {
      int n = n0 + (tx << 2) + j;
      if (n < N) {
        float v = acc[r][j];
        if (HASBIAS) v += bias[n];
        if (ACT == 1) v = fmaxf(v, 0.f);
        if (ACT == 2) v = softplusf(v);
        out[(size_t)m * N + n] = v;
      }
    }
  }
}

// ---------------- xs = skip + pos ----------------
__global__ __launch_bounds__(256) void addpos_k(const float* __restrict__ a,
                                                const float* __restrict__ pos,
                                                float* __restrict__ o) {
  int i = blockIdx.x * 256 + threadIdx.x;
  o[i] = a[i] + pos[i & 65535];
}

// ---------------- causal depthwise conv1d(k=4) + silu ----------------
__global__ __launch_bounds__(256) void conv1d_silu_k(const float* __restrict__ xz,
                                                     const float* __restrict__ w,
                                                     const float* __restrict__ cb,
                                                     float* __restrict__ xc) {
  int i = blockIdx.x * 256 + threadIdx.x;  // over 2048*512
  int m = i >> 9, d = i & 511;
  int b = m >> 8, l = m & 255;
  float s = cb[d];
#pragma unroll
  for (int j = 0; j < 4; ++j) {
    int ll = l - 3 + j;
    if (ll >= 0) s = fmaf(w[(d << 2) + j], xz[((size_t)((b << 8) + ll) << 10) + d], s);
  }
  xc[(size_t)m * 512 + d] = siluf(s);
}

// ---------------- selective scan, windowed (16-step windows, spill-free) ----------------
__global__ __launch_bounds__(256, 1) void scan_k(const float* __restrict__ dt,
                                                 const float* __restrict__ u,
                                                 const float* __restrict__ xdbl,
                                                 const float* __restrict__ Alog,
                                                 const float* __restrict__ Dp,
                                                 const float* __restrict__ xz,
                                                 float* __restrict__ yg) {
  __shared__ float pbuf[4][2][16][33];
  int tid  = threadIdx.x;
  int widx = tid >> 6, lane = tid & 63;
  int wid  = (blockIdx.x << 2) + widx;
  int n = lane & 31, ch = lane >> 5;
  int d0 = (wid & 255) << 1;
  int d = d0 + ch;
  int b = wid >> 8;
  size_t base = (size_t)b << 8;
  float Av = -__expf(Alog[(d << 5) + n]);
  float Dv0 = Dp[d0], Dv1 = Dp[d0 + 1];
  float h = 0.f;
  int row = lane & 31;
  int rch = row >> 4, rlp = row & 15;
  int nh  = lane >> 5;
  int drow = d0 + rch;
  float Dsel = rch ? Dv1 : Dv0;

  for (int w0 = 0; w0 < 256; w0 += 16) {
    float dA[16], dBu[16], Cv[16];
#pragma unroll
    for (int j = 0; j < 16; ++j) {
      size_t r = base + w0 + j;
      float dtv = dt[(r << 9) + d];
      float uv  = u [(r << 9) + d];
      float Bv  = xdbl[r * 80 + 16 + n];
      Cv[j]     = xdbl[r * 80 + 48 + n];
      dA[j]  = __expf(dtv * Av);
      dBu[j] = dtv * Bv * uv;
    }
#pragma unroll
    for (int j = 0; j < 16; ++j) {
      h = fmaf(dA[j], h, dBu[j]);
      pbuf[widx][ch][j][n] = h * Cv[j];
    }
    __syncthreads();
    float s = 0.f;
#pragma unroll
    for (int nn = 0; nn < 16; ++nn) s += pbuf[widx][rch][rlp][(nh << 4) + nn];
    s += __shfl_xor(s, 32);
    if (lane < 32) {
      size_t r = base + w0 + rlp;
      float uv = u[(r << 9) + drow];
      float zv = xz[(r << 10) + 512 + drow];
      yg[(r << 9) + drow] = (s + uv * Dsel) * siluf(zv);
    }
    __syncthreads();
  }
}

// ---------------- cat = [xs2 | skip] ----------------
__global__ __launch_bounds__(256) void concat_k(const float* __restrict__ a,
                                                const float* __restrict__ b,
                                                float* __restrict__ o) {
  int i = blockIdx.x * 256 + threadIdx.x;  // 2048*512
  int m = i >> 9, j = i & 511;
  o[i] = (j < 256) ? a[(size_t)m * 256 + j] : b[(size_t)m * 256 + j - 256];
}

// ---------------- direct 3x3 conv (IC=1 only), relu ----------------
template <int IC>
__global__ __launch_bounds__(256) void conv3x3_k(const float* __restrict__ in,
                                                 const float* __restrict__ w,
                                                 const float* __restrict__ bias,
                                                 float* __restrict__ out) {
  __shared__ float t[IC][6][68];
  __shared__ float wl[IC * 144];
  __shared__ float bl[16];
  int bid = blockIdx.x;
  int x0 = (bid & 3) << 6;
  int y0 = ((bid >> 2) & 63) << 2;
  int bb = bid >> 8;
  int tid = threadIdx.x;
  for (int i = tid; i < IC * 144; i += 256) {
    int oc = i & 15, t2 = i >> 4;
    wl[i] = w[(size_t)oc * (IC * 9) + t2];
  }
  if (tid < 16) bl[tid] = bias[tid];
  for (int i = tid; i < IC * 396; i += 256) {
    int ic = i / 396, rem = i - ic * 396;
    int r = rem / 66, cx = rem - r * 66;
    int y = y0 - 1 + r, xx = x0 - 1 + cx;
    float v = 0.f;
    if (y >= 0 && y < 256 && xx >= 0 && xx < 256)
      v = in[(((size_t)bb * IC + ic) << 16) + (y << 8) + xx];
    t[ic][r][cx] = v;
  }
  __syncthreads();
  int tx = tid & 15, row = (tid >> 4) & 3, ocq = tid >> 6;
  float acc[4][4];
#pragma unroll
  for (int o = 0; o < 4; ++o)
#pragma unroll
    for (int p = 0; p < 4; ++p) acc[o][p] = 0.f;

  for (int ic = 0; ic < IC; ++ic) {
#pragma unroll
    for (int dy = 0; dy < 3; ++dy) {
      const float* rp = &t[ic][row + dy][tx << 2];
      float rv[6];
#pragma unroll
      for (int q = 0; q < 6; ++q) rv[q] = rp[q];
#pragma unroll
      for (int dx = 0; dx < 3; ++dx) {
        const float* wp4 = &wl[(((ic * 3 + dy) * 3 + dx) << 4) + (ocq << 2)];
#pragma unroll
        for (int o = 0; o < 4; ++o) {
          float wv = wp4[o];
#pragma unroll
          for (int p = 0; p < 4; ++p) acc[o][p] = fmaf(rv[p + dx], wv, acc[o][p]);
        }
      }
    }
  }
  int xo = x0 + (tx << 2), yo = y0 + row;
#pragma unroll
  for (int o = 0; o < 4; ++o) {
    int oc = (ocq << 2) + o;
    float4 v4;
    v4.x = fmaxf(acc[o][0] + bl[oc], 0.f);
    v4.y = fmaxf(acc[o][1] + bl[oc], 0.f);
    v4.z = fmaxf(acc[o][2] + bl[oc], 0.f);
    v4.w = fmaxf(acc[o][3] + bl[oc], 0.f);
    *(float4*)&out[(((size_t)bb * 16 + oc) << 16) + (yo << 8) + xo] = v4;
  }
}

// ---------------- MFMA implicit-GEMM 3x3 conv, IC=OC=16, relu ----------------
__global__ __launch_bounds__(256, 2) void conv_mfma(const float* __restrict__ in,
                                                    const unsigned short* __restrict__ wth,
                                                    const unsigned short* __restrict__ wtl,
                                                    const float* __restrict__ bias,
                                                    float* __restrict__ out) {
  __shared__ __align__(16) char smem[58752];
  unsigned short* inh = (unsigned short*)smem;          // 14688 elems
  unsigned short* inl = inh + 14688;                    // 14688 elems
  int bid = blockIdx.x;
  int txi = bid & 7;            // x tile (32 px)
  int tyi = (bid >> 3) & 15;    // y tile (16 px)
  int bb  = bid >> 7;
  int x0 = txi << 5, y0 = tyi << 4;
  int tid = threadIdx.x;

  for (int i = tid; i < 9792; i += 256) {     // 16 ic x 18 y x 34 x
    int ic = i / 612, rem = i - ic * 612;
    int y = rem / 34, xx = rem - y * 34;
    int gy = y0 + y - 1, gx = x0 + xx - 1;
    float v = 0.f;
    if (gy >= 0 && gy < 256 && gx >= 0 && gx < 256)
      v = in[(((size_t)bb * 16 + ic) << 16) + (gy << 8) + gx];
    short hh, ll; split2(v, hh, ll);
    int a = (y * 34 + xx) * 24 + ic;
    inh[a] = (unsigned short)hh; inl[a] = (unsigned short)ll;
  }
  __syncthreads();

  int lane = tid & 63, w = tid >> 6;
  int fi = lane & 15, fq = lane >> 4;
  int fqh = fq >> 1, ich8 = (fq & 1) << 3;

  int adel[5];
#pragma unroll
  for (int s = 0; s < 5; ++s) {
    int dydx = 2 * s + fqh;
    if (dydx > 8) dydx = 8;
    int dy = dydx / 3, dx = dydx - dy * 3;
    adel[s] = (dy * 34 + dx) * 24;
  }
  int abase[8];
#pragma unroll
  for (int q = 0; q < 8; ++q) {
    int px = ((w * 8 + q) << 4) + fi;
    int y = px >> 5, xx = px & 31;
    abase[q] = (y * 34 + xx) * 24 + ich8;
  }
  short8v bh[5], bl[5];
#pragma unroll
  for (int s = 0; s < 5; ++s) {
    int slot = ((s * 4 + fq) * 16 + fi) * 8;
    bh[s] = *(const short8v*)(wth + slot);
    bl[s] = *(const short8v*)(wtl + slot);
  }

  f32x4 acc[8];
#pragma unroll
  for (int q = 0; q < 8; ++q) acc[q] = (f32x4)(0.f);

#pragma unroll
  for (int s = 0; s < 5; ++s) {
#pragma unroll
    for (int q = 0; q < 8; ++q) {
      short8v ah = *(const short8v*)&inh[abase[q] + adel[s]];
      short8v al = *(const short8v*)&inl[abase[q] + adel[s]];
      MFMA3(acc[q], ah, al, bh[s], bl[s]);
    }
  }
  __syncthreads();

  float* outs = (float*)smem;
#pragma unroll
  for (int q = 0; q < 8; ++q) {
    int pxb = ((w * 8 + q) << 4) + (fq << 2);
#pragma unroll
    for (int r = 0; r < 4; ++r)
      outs[fi * 514 + pxb + r] = acc[q][r];
  }
  __syncthreads();
  for (int i = tid; i < 8192; i += 256) {
    int oc = i >> 9, px = i & 511;
    int y = px >> 5, xx = px & 31;
    float v = fmaxf(outs[oc * 514 + px] + bias[oc], 0.f);
    out[(((size_t)bb * 16 + oc) << 16) + ((y0 + y) << 8) + x0 + xx] = v;
  }
}

// ---------------- 2x2 mean pool + 1x1 conv (16->1) ----------------
__global__ __launch_bounds__(256) void pool_c4_k(const float* __restrict__ in,
                                                 const float* __restrict__ w4,
                                                 const float* __restrict__ b4,
                                                 float* __restrict__ out) {
  int i = blockIdx.x * 256 + threadIdx.x;  // 8*128*128
  int x = i & 127, y = (i >> 7) & 127, b = i >> 14;
  float s = b4[0];
#pragma unroll
  for (int ic = 0; ic < 16; ++ic) {
    const float* p = in + (((size_t)b * 16 + ic) << 16) + ((size_t)(y << 1) << 8) + (x << 1);
    float m4 = 0.25f * (p[0] + p[1] + p[256] + p[257]);
    s = fmaf(w4[ic], m4, s);
  }
  out[i] = s;
}

// ---------------- launcher ----------------
extern "C" void kernel_launch(void* const* d_in, const int* in_sizes, int n_in,
                              void* d_out, int out_size, void* d_ws, size_t ws_size,
                              hipStream_t stream) {
  const float* x        = (const float*)d_in[0];
  const float* lin0_w   = (const float*)d_in[1];
  const float* lin0_b   = (const float*)d_in[2];
  const float* ln0_g    = (const float*)d_in[3];
  const float* ln0_bb   = (const float*)d_in[4];
  const float* lin1_w   = (const float*)d_in[5];
  const float* lin1_b   = (const float*)d_in[6];
  const float* ln1_g    = (const float*)d_in[7];
  const float* ln1_bb   = (const float*)d_in[8];
  const float* pos      = (const float*)d_in[9];
  const float* m_in_w   = (const float*)d_in[10];
  const float* m_conv_w = (const float*)d_in[11];
  const float* m_conv_b = (const float*)d_in[12];
  const float* m_xproj_w= (const float*)d_in[13];
  const float* m_dt_w   = (const float*)d_in[14];
  const float* m_dt_b   = (const float*)d_in[15];
  const float* m_Alog   = (const float*)d_in[16];
  const float* m_D      = (const float*)d_in[17];
  const float* m_out_w  = (const float*)d_in[18];
  const float* blk_w    = (const float*)d_in[19];
  const float* blk_b    = (const float*)d_in[20];
  const float* dec_w    = (const float*)d_in[21];
  const float* dec_b    = (const float*)d_in[22];
  const float* c1_w     = (const float*)d_in[23];
  const float* c1_b     = (const float*)d_in[24];
  const float* c2_w     = (const float*)d_in[25];
  const float* c2_b     = (const float*)d_in[26];
  const float* c3_w     = (const float*)d_in[27];
  const float* c3_b     = (const float*)d_in[28];
  const float* c4_w     = (const float*)d_in[29];
  const float* c4_b     = (const float*)d_in[30];

  float* ws  = (float*)d_ws;
  float* out = (float*)d_out;

  unsigned short* wt0h = (unsigned short*)(ws + F_WT0);
  unsigned short* wt0l = wt0h + 4194304;
  unsigned short* wmed = (unsigned short*)(ws + F_WMED);
  unsigned short* inw_h = wmed,           * inw_l = wmed + 262144;   // m_in_w 1024x256
  unsigned short* l1_h  = wmed + 524288,  * l1_l  = wmed + 589824;   // lin1_w 256x256
  unsigned short* ow_h  = wmed + 655360,  * ow_l  = wmed + 786432;   // m_out_w 256x512
  unsigned short* bk_h  = wmed + 917504,  * bk_l  = wmed + 983040;   // blk_w 256x256
  unsigned short* dc_h  = wmed + 1048576, * dc_l  = wmed + 1179648;  // dec_w 256x512
  unsigned short* wc2h  = wmed + 1310720, * wc2l  = wmed + 1313280;  // conv2 tiles
  unsigned short* wc3h  = wmed + 1315840, * wc3l  = wmed + 1318400;  // conv3 tiles

  // 1. weight tiling (split bf16, LDS/frag-image layout)
  tile_w_lin0<<<512, 256, 0, stream>>>(lin0_w, wt0h, wt0l);
  tile_w_med<<<128, 256, 0, stream>>>(m_in_w, inw_h, inw_l, 256, 32768);
  tile_w_med<<<32, 256, 0, stream>>>(lin1_w, l1_h, l1_l, 256, 8192);
  tile_w_med<<<64, 256, 0, stream>>>(m_out_w, ow_h, ow_l, 512, 16384);
  tile_w_med<<<32, 256, 0, stream>>>(blk_w, bk_h, bk_l, 256, 8192);
  tile_w_med<<<64, 256, 0, stream>>>(dec_w, dc_h, dc_l, 512, 16384);
  tile_w_conv<<<2, 256, 0, stream>>>(c2_w, wc2h, wc2l);
  tile_w_conv<<<2, 256, 0, stream>>>(c3_w, wc3h, wc3l);
  // 2. lin0 MFMA GEMM -> 32 partial slabs (256x256 tile, 256 blocks = 1/CU)
  lin0_mfma<<<256, 512, 0, stream>>>(x, wt0h, wt0l, ws);
  // 3. reduce 32 + bias + relu + LN0 -> xt0
  ln32_k<<<MROWS, 256, 0, stream>>>(ws + F_PART, ws, lin0_b, ln0_g, ln0_bb, ws + F_XT0);
  // 4. lin1 -> part (raw) ; 5. bias+relu+LN1 -> skip
  med_mfma<0, 0><<<dim3(2, 32), 256, 0, stream>>>(ws + F_XT0, 256, l1_h, l1_l, nullptr,
                                                  ws + F_PART, 256, 256);
  ln_k<<<MROWS, 256, 0, stream>>>(ws + F_PART, 1, lin1_b, ln1_g, ln1_bb, ws + F_SKIP);
  // 6. xs = skip + pos
  addpos_k<<<2048, 256, 0, stream>>>(ws + F_SKIP, pos, ws + F_XS);
  // 7. xz = xs @ m_in_w^T  [2048,1024]
  med_mfma<0, 0><<<dim3(8, 32), 256, 0, stream>>>(ws + F_XS, 256, inw_h, inw_l, nullptr,
                                                  ws + F_XZ, 256, 1024);
  // 8. causal dwconv + silu -> xc
  conv1d_silu_k<<<4096, 256, 0, stream>>>(ws + F_XZ, m_conv_w, m_conv_b, ws + F_XC);
  // 9. x_dbl = xc @ m_xproj_w^T  [2048,80]
  gemm_k<2, 0, 0><<<dim3(2, 64), 256, 0, stream>>>(ws + F_XC, 512, m_xproj_w, nullptr,
                                                   ws + F_XDBL, MROWS, 80, 512);
  // 10. dt = softplus(x_dbl[:, :16] @ m_dt_w^T + m_dt_b)
  gemm_k<2, 2, 1><<<dim3(8, 64), 256, 0, stream>>>(ws + F_XDBL, 80, m_dt_w, m_dt_b,
                                                   ws + F_DT, MROWS, 512, 16);
  // 11. selective scan + silu(z) gating -> yg
  scan_k<<<512, 256, 0, stream>>>(ws + F_DT, ws + F_XC, ws + F_XDBL, m_Alog, m_D,
                                  ws + F_XZ, ws + F_YG);
  // 12. ym = yg @ m_out_w^T
  med_mfma<0, 0><<<dim3(2, 32), 256, 0, stream>>>(ws + F_YG, 512, ow_h, ow_l, nullptr,
                                                  ws + F_YM, 512, 256);
  // 13. xs2 = ym @ blk_w^T + blk_b
  med_mfma<0, 1><<<dim3(2, 32), 256, 0, stream>>>(ws + F_YM, 256, bk_h, bk_l, blk_b,
                                                  ws + F_XS2, 256, 256);
  // 14. cat = [xs2 | skip]
  concat_k<<<4096, 256, 0, stream>>>(ws + F_XS2, ws + F_SKIP, ws + F_CAT);
  // 15. dec = relu(cat @ dec_w^T + dec_b)
  med_mfma<1, 1><<<dim3(2, 32), 256, 0, stream>>>(ws + F_CAT, 512, dc_h, dc_l, dec_b,
                                                  ws + F_DEC, 512, 256);
  // 16. conv1 (IC=1, scalar)
  conv3x3_k<1><<<2048, 256, 0, stream>>>(ws + F_DEC, c1_w, c1_b, ws + F_C1);
  // 17-18. conv2/conv3 via MFMA implicit GEMM
  conv_mfma<<<1024, 256, 0, stream>>>(ws + F_C1, wc2h, wc2l, c2_b, ws + F_C2);
  conv_mfma<<<1024, 256, 0, stream>>>(ws + F_C2, wc3h, wc3l, c3_b, ws + F_C3);
  // 19. pool + 1x1 conv -> out
  pool_c4_k<<<512, 256, 0, stream>>>(ws + F_C3, c4_w, c4_b, out);
}

// Round 9
// 375.834 us; speedup vs baseline: 1.0085x; 1.0085x over previous
//
#include <hip/hip_runtime.h>
#include <hip/hip_bf16.h>
#include <cstddef>
#include <cstdint>

// ---------------- problem constants ----------------
#define MROWS 2048           // B8*L256
#define KBIG  16384          // DIN*CH32

typedef __attribute__((ext_vector_type(8))) short short8v;
typedef __attribute__((ext_vector_type(4))) float f32x4;
typedef unsigned int u32;

// ---------------- ws layout (float offsets) ----------------
static const size_t F_XT0  = 0;          // 2048*256
static const size_t F_SKIP = 524288;     // 2048*256
static const size_t F_XS   = 1048576;    // 2048*256
static const size_t F_XZ   = 1572864;    // 2048*1024
static const size_t F_XC   = 3670016;    // 2048*512
static const size_t F_XDBL = 4718592;    // 2048*64 (BC only)
static const size_t F_DT   = 4882432;    // 2048*512
static const size_t F_YG   = 5931008;    // 2048*512
static const size_t F_YM   = 6979584;    // 2048*256
static const size_t F_XS2  = 7503872;    // 2048*256
static const size_t F_CAT  = 8028160;    // (unused now)
static const size_t F_DEC  = 9076736;    // 2048*256 (ends 9601024)
static const size_t F_WMED = 9700000;    // med W tiles + conv W tiles
static const size_t F_WT0  = 10485760;   // lin0 split-bf16 tiles (ends 14680064)
static const size_t F_PART = 14680064;   // lin0 partial slabs 0-15 (ends 23068672)
// lin0 partial slabs 16-31 live at float offset 0 (early chain region, free during lin0).
static const size_t F_WDT  = 23068672;   // dt fused-weight tiles: 262144 floats (ws >= 512MB per fill evidence)
static const size_t F_C1   = 10485760;   // conv ping-pong (aliases WT0+PART, dead by then)
static const size_t F_C2   = 0;
static const size_t F_C3   = 14680064;

__device__ __forceinline__ float siluf(float v)     { return v / (1.f + __expf(-v)); }
__device__ __forceinline__ float softplusf(float v) { return v > 20.f ? v : log1pf(__expf(v)); }

__device__ __forceinline__ void split2(float v, short& h, short& l) {
  __hip_bfloat16 hb = __float2bfloat16(v);
  float hf = __bfloat162float(hb);
  __hip_bfloat16 lb = __float2bfloat16(v - hf);
  h = *(short*)&hb; l = *(short*)&lb;
}

__device__ __forceinline__ void glds16(const void* g, void* l) {
  __builtin_amdgcn_global_load_lds((const __attribute__((address_space(1))) u32*)g,
                                   (__attribute__((address_space(3))) u32*)l, 16, 0, 0);
}

#define MFMA3(acc, ah, al, bh, bl)                                            \
  acc = __builtin_amdgcn_mfma_f32_16x16x32_bf16(ah, bh, acc, 0, 0, 0);        \
  acc = __builtin_amdgcn_mfma_f32_16x16x32_bf16(al, bh, acc, 0, 0, 0);        \
  acc = __builtin_amdgcn_mfma_f32_16x16x32_bf16(ah, bl, acc, 0, 0, 0);

// ---------------- device helpers for weight tiling ----------------
__device__ __forceinline__ void med_tile_blk(const float* w, unsigned short* th,
                                             unsigned short* tl, int K, int nslots, int b) {
  int slot = b * 256 + threadIdx.x;
  if (slot >= nslots) return;
  int NS = K >> 5;
  int col = slot & 127, kg = (slot >> 7) & 3, rest = slot >> 9;
  int s = rest % NS, nt = rest / NS;
  const float* src = w + (size_t)(nt * 128 + col) * K + (s << 5) + (kg << 3);
  short8v h8, l8;
#pragma unroll
  for (int j = 0; j < 8; ++j) {
    short hh, ll; split2(src[j], hh, ll);
    h8[j] = hh; l8[j] = ll;
  }
  *(short8v*)(th + (size_t)slot * 8) = h8;
  *(short8v*)(tl + (size_t)slot * 8) = l8;
}

__device__ __forceinline__ void conv_tile_blk(const float* w, unsigned short* th,
                                              unsigned short* tl, int b) {
  int slot = b * 256 + threadIdx.x;   // 320 slots
  if (slot >= 320) return;
  int oc = slot & 15;
  int sfq = slot >> 4;
  int s = sfq >> 2, fq = sfq & 3;
  short8v h8, l8;
#pragma unroll
  for (int j = 0; j < 8; ++j) {
    int k = s * 32 + fq * 8 + j;
    float v = 0.f;
    if (k < 144) {
      int dydx = k >> 4, ic = k & 15;
      v = w[oc * 144 + ic * 9 + dydx];
    }
    short hh, ll; split2(v, hh, ll);
    h8[j] = hh; l8[j] = ll;
  }
  *(short8v*)(th + (size_t)slot * 8) = h8;
  *(short8v*)(tl + (size_t)slot * 8) = l8;
}

// W'[d][k] = sum_{r<16} m_dt_w[d][r] * m_xproj_w[r][k]; tiled like med (K=512)
__device__ __forceinline__ void wdt_tile_blk(const float* dtw, const float* xpw,
                                             unsigned short* th, unsigned short* tl, int b) {
  int slot = b * 256 + threadIdx.x;   // 32768 slots
  int col = slot & 127, kg = (slot >> 7) & 3, rest = slot >> 9;
  int s = rest & 15, nt = rest >> 4;  // NS = 16
  int d = nt * 128 + col;
  float wrow[16];
#pragma unroll
  for (int r = 0; r < 16; ++r) wrow[r] = dtw[d * 16 + r];
  short8v h8, l8;
#pragma unroll
  for (int j = 0; j < 8; ++j) {
    int k = s * 32 + kg * 8 + j;
    float v = 0.f;
#pragma unroll
    for (int r = 0; r < 16; ++r) v = fmaf(wrow[r], xpw[r * 512 + k], v);
    short hh, ll; split2(v, hh, ll);
    h8[j] = hh; l8[j] = ll;
  }
  *(short8v*)(th + (size_t)slot * 8) = h8;
  *(short8v*)(tl + (size_t)slot * 8) = l8;
}

// ---------------- mega weight-tiling kernel (all weight prep in ONE launch) ----------------
__global__ __launch_bounds__(256) void tile_all(const float* __restrict__ lin0_w,
                                                unsigned short* __restrict__ wt0h,
                                                unsigned short* __restrict__ wt0l,
                                                unsigned short* __restrict__ wmed,
                                                const float* __restrict__ m_in_w,
                                                const float* __restrict__ lin1_w,
                                                const float* __restrict__ m_out_w,
                                                const float* __restrict__ blk_w,
                                                const float* __restrict__ dec_w,
                                                const float* __restrict__ c2_w,
                                                const float* __restrict__ c3_w,
                                                const float* __restrict__ m_dt_w,
                                                const float* __restrict__ m_xproj_w,
                                                unsigned short* __restrict__ wdth,
                                                unsigned short* __restrict__ wdtl) {
  __shared__ float ls[32 * 264];
  int b = blockIdx.x;
  int tid = threadIdx.x;
  if (b < 512) {
    // lin0 transpose-tile: Wt[slot=(k'>>3)*256+col][j], k'=c*512+f, k=f*32+c
    int ct = b >> 6, kt = b & 63;
    int c0 = ct << 5, k0 = kt << 8;
    for (int u = tid; u < 2048; u += 256) {
      int col_l = u >> 6, f4i = u & 63;
      int k_l = f4i << 2;
      float4 v = *(const float4*)(lin0_w + (size_t)(c0 + col_l) * KBIG + k0 + k_l);
      float vv[4] = {v.x, v.y, v.z, v.w};
#pragma unroll
      for (int j = 0; j < 4; ++j) {
        int idx = k_l + j;
        ls[col_l * 264 + idx + (idx >> 5)] = vv[j];
      }
    }
    __syncthreads();
    for (int oi = tid; oi < 1024; oi += 256) {
      int col_l = oi & 31, c = oi >> 5;
      short8v h8, l8;
#pragma unroll
      for (int j = 0; j < 8; ++j) {
        float v = ls[col_l * 264 + j * 33 + c];
        short hh, ll; split2(v, hh, ll);
        h8[j] = hh; l8[j] = ll;
      }
      size_t slot = ((size_t)(c * 64 + kt)) * 256 + c0 + col_l;
      *(short8v*)(wt0h + slot * 8) = h8;
      *(short8v*)(wt0l + slot * 8) = l8;
    }
    return;
  }
  b -= 512;
  if (b < 128) { med_tile_blk(m_in_w,  wmed,           wmed + 262144,  256, 32768, b); return; }
  b -= 128;
  if (b < 32)  { med_tile_blk(lin1_w,  wmed + 524288,  wmed + 589824,  256, 8192,  b); return; }
  b -= 32;
  if (b < 64)  { med_tile_blk(m_out_w, wmed + 655360,  wmed + 786432,  512, 16384, b); return; }
  b -= 64;
  if (b < 32)  { med_tile_blk(blk_w,   wmed + 917504,  wmed + 983040,  256, 8192,  b); return; }
  b -= 32;
  if (b < 64)  { med_tile_blk(dec_w,   wmed + 1048576, wmed + 1179648, 512, 16384, b); return; }
  b -= 64;
  if (b < 2)   { conv_tile_blk(c2_w, wmed + 1310720, wmed + 1313280, b); return; }
  b -= 2;
  if (b < 2)   { conv_tile_blk(c3_w, wmed + 1315840, wmed + 1318400, b); return; }
  b -= 2;
  wdt_tile_blk(m_dt_w, m_xproj_w, wdth, wdtl, b);   // 128 blocks
}

// ---------------- lin0 MFMA GEMM: BM=256, BN=256(full), BK=32, split-K=32 ----------------
__global__ __launch_bounds__(512, 2) void lin0_mfma(const float* __restrict__ x,
                                                    const unsigned short* __restrict__ wh,
                                                    const unsigned short* __restrict__ wl,
                                                    float* __restrict__ wsbase) {
  __shared__ short8v Ad[2][2][1024];
  __shared__ short8v Bd[2][2][1024];
  int bid = blockIdx.x;
  int mt = bid >> 5, z = bid & 31;
  int tid = threadIdx.x;
  int lane = tid & 63, wid = tid >> 6;
  int wm = wid >> 2, wn = wid & 3;
  int fi = lane & 15, fq = lane >> 4;
  int arow = tid >> 1, kh = tid & 1;
  const float* xrow = x + (size_t)mt * 4194304 + (size_t)z * 131072 + (size_t)arow * 512;
  int skg = wid & 3, shl = wid >> 2;
  const unsigned short* wsrc = shl ? wl : wh;
  int aoff[8], boff[4];
#pragma unroll
  for (int mi = 0; mi < 8; ++mi) {
    int row = wm * 128 + mi * 16 + fi;
    aoff[mi] = fq * 256 + (row ^ (fq << 2));
  }
#pragma unroll
  for (int ni = 0; ni < 4; ++ni) boff[ni] = fq * 256 + wn * 64 + ni * 16 + fi;

  f32x4 acc[8][4];
#pragma unroll
  for (int mi = 0; mi < 8; ++mi)
#pragma unroll
    for (int ni = 0; ni < 4; ++ni) acc[mi][ni] = (f32x4)(0.f);

  {
    int slotbase = ((z * 16 + 0) * 4 + skg) * 256;
#pragma unroll
    for (int q = 0; q < 4; ++q)
      glds16(wsrc + (size_t)(slotbase + q * 64 + lane) * 8,
             (void*)&Bd[0][shl][skg * 256 + q * 64]);
    int f0 = kh << 4;
    float vv[16];
#pragma unroll
    for (int j4 = 0; j4 < 4; ++j4) {
      float4 v = *(const float4*)(xrow + f0 + 4 * j4);
      vv[4 * j4] = v.x; vv[4 * j4 + 1] = v.y; vv[4 * j4 + 2] = v.z; vv[4 * j4 + 3] = v.w;
    }
#pragma unroll
    for (int jg = 0; jg < 2; ++jg) {
      short8v h8, l8;
#pragma unroll
      for (int j = 0; j < 8; ++j) { short hh, ll; split2(vv[jg * 8 + j], hh, ll); h8[j] = hh; l8[j] = ll; }
      int kg = (kh << 1) + jg;
      int idx = kg * 256 + (arow ^ (kg << 2));
      Ad[0][0][idx] = h8; Ad[0][1][idx] = l8;
    }
    __syncthreads();
  }

  for (int s = 0; s < 16; ++s) {
    int cb = s & 1, nb = cb ^ 1;
    bool more = s < 15;
    float vv[16];
    if (more) {
      int slotbase = ((z * 16 + s + 1) * 4 + skg) * 256;
#pragma unroll
      for (int q = 0; q < 4; ++q)
        glds16(wsrc + (size_t)(slotbase + q * 64 + lane) * 8,
               (void*)&Bd[nb][shl][skg * 256 + q * 64]);
      int f0 = ((s + 1) << 5) + (kh << 4);
#pragma unroll
      for (int j4 = 0; j4 < 4; ++j4) {
        float4 v = *(const float4*)(xrow + f0 + 4 * j4);
        vv[4 * j4] = v.x; vv[4 * j4 + 1] = v.y; vv[4 * j4 + 2] = v.z; vv[4 * j4 + 3] = v.w;
      }
    }
    short8v fah[8], fal[8];
#pragma unroll
    for (int mi = 0; mi < 8; ++mi) { fah[mi] = Ad[cb][0][aoff[mi]]; fal[mi] = Ad[cb][1][aoff[mi]]; }
#pragma unroll
    for (int ni = 0; ni < 4; ++ni) {
      short8v bh = Bd[cb][0][boff[ni]];
      short8v bl = Bd[cb][1][boff[ni]];
#pragma unroll
      for (int mi = 0; mi < 8; ++mi) { MFMA3(acc[mi][ni], fah[mi], fal[mi], bh, bl); }
    }
    if (more) {
#pragma unroll
      for (int jg = 0; jg < 2; ++jg) {
        short8v h8, l8;
#pragma unroll
        for (int j = 0; j < 8; ++j) { short hh, ll; split2(vv[jg * 8 + j], hh, ll); h8[j] = hh; l8[j] = ll; }
        int kg = (kh << 1) + jg;
        int idx = kg * 256 + (arow ^ (kg << 2));
        Ad[nb][0][idx] = h8; Ad[nb][1][idx] = l8;
      }
    }
    __syncthreads();
  }

  size_t slabbase = (z < 16) ? (F_PART + (size_t)z * 524288) : ((size_t)(z - 16) * 524288);
  float* po = wsbase + slabbase + (size_t)mt * 65536;
#pragma unroll
  for (int mi = 0; mi < 8; ++mi)
#pragma unroll
    for (int ni = 0; ni < 4; ++ni) {
      int mloc = wm * 128 + mi * 16 + fq * 4;
      int n = wn * 64 + ni * 16 + fi;
#pragma unroll
      for (int r = 0; r < 4; ++r)
        po[(size_t)(mloc + r) * 256 + n] = acc[mi][ni][r];
    }
}

// ---------------- medium MFMA GEMM: BM=64, BN=128, BK=32 (SRC2: split A source) ----------------
template <int ACT, int HASBIAS, int SRC2>
__global__ __launch_bounds__(256, 2) void med_mfma(const float* __restrict__ A, int lda,
                                                   const float* __restrict__ A2,
                                                   const unsigned short* __restrict__ wh,
                                                   const unsigned short* __restrict__ wl,
                                                   const float* __restrict__ bias,
                                                   float* __restrict__ out,
                                                   int K, int N) {
  __shared__ short8v Ahs[256], Als[256];
  __shared__ short8v Bd[2][2][512];
  int nt = blockIdx.x, mt = blockIdx.y;
  int NS = K >> 5;
  int tid = threadIdx.x;
  int lane = tid & 63, wid = tid >> 6;
  int fi = lane & 15, fq = lane >> 4;
  int arow = tid >> 2, akg = tid & 3;
  int awidx = akg * 64 + (arow ^ (akg << 2));
  int m0 = mt << 6;
  size_t wtbase = (size_t)nt * NS;
  int aoff[4], boff[2];
#pragma unroll
  for (int mi = 0; mi < 4; ++mi) {
    int row = mi * 16 + fi;
    aoff[mi] = fq * 64 + (row ^ (fq << 2));
  }
#pragma unroll
  for (int ni = 0; ni < 2; ++ni) boff[ni] = fq * 128 + wid * 32 + ni * 16 + fi;

  f32x4 acc[4][2];
#pragma unroll
  for (int mi = 0; mi < 4; ++mi)
#pragma unroll
    for (int ni = 0; ni < 2; ++ni) acc[mi][ni] = (f32x4)(0.f);

  {
#pragma unroll
    for (int p = 0; p < 2; ++p) {
      int q = (wid << 1) + p;
      size_t gb = wtbase * 8192 + (size_t)q * 1024 + (size_t)lane * 16;
      glds16((const char*)wh + gb, (char*)&Bd[0][0][0] + q * 1024);
      glds16((const char*)wl + gb, (char*)&Bd[0][1][0] + q * 1024);
    }
    const float* gp = A + (size_t)(m0 + arow) * lda + (akg << 3);
    float4 v0 = *(const float4*)gp, v1 = *(const float4*)(gp + 4);
    float vv[8] = {v0.x, v0.y, v0.z, v0.w, v1.x, v1.y, v1.z, v1.w};
    short8v h8, l8;
#pragma unroll
    for (int j = 0; j < 8; ++j) { short hh, ll; split2(vv[j], hh, ll); h8[j] = hh; l8[j] = ll; }
    Ahs[awidx] = h8; Als[awidx] = l8;
    __syncthreads();
  }

  for (int s = 0; s < NS; ++s) {
    int cb = s & 1, nb = cb ^ 1;
    bool more = (s + 1) < NS;
    float4 v0, v1;
    if (more) {
#pragma unroll
      for (int p = 0; p < 2; ++p) {
        int q = (wid << 1) + p;
        size_t gb = (wtbase + s + 1) * 8192 + (size_t)q * 1024 + (size_t)lane * 16;
        glds16((const char*)wh + gb, (char*)&Bd[nb][0][0] + q * 1024);
        glds16((const char*)wl + gb, (char*)&Bd[nb][1][0] + q * 1024);
      }
      int sk = (s + 1) << 5;
      const float* gp;
      if (SRC2 && sk >= 256)
        gp = A2 + (size_t)(m0 + arow) * 256 + (sk - 256) + (akg << 3);
      else
        gp = A + (size_t)(m0 + arow) * lda + sk + (akg << 3);
      v0 = *(const float4*)gp; v1 = *(const float4*)(gp + 4);
    }
    short8v fah[4], fal[4];
#pragma unroll
    for (int mi = 0; mi < 4; ++mi) { fah[mi] = Ahs[aoff[mi]]; fal[mi] = Als[aoff[mi]]; }
#pragma unroll
    for (int ni = 0; ni < 2; ++ni) {
      short8v bh = Bd[cb][0][boff[ni]];
      short8v bl = Bd[cb][1][boff[ni]];
#pragma unroll
      for (int mi = 0; mi < 4; ++mi) { MFMA3(acc[mi][ni], fah[mi], fal[mi], bh, bl); }
    }
    __syncthreads();
    if (more) {
      float vv[8] = {v0.x, v0.y, v0.z, v0.w, v1.x, v1.y, v1.z, v1.w};
      short8v h8, l8;
#pragma unroll
      for (int j = 0; j < 8; ++j) { short hh, ll; split2(vv[j], hh, ll); h8[j] = hh; l8[j] = ll; }
      Ahs[awidx] = h8; Als[awidx] = l8;
    }
    __syncthreads();
  }

#pragma unroll
  for (int mi = 0; mi < 4; ++mi)
#pragma unroll
    for (int ni = 0; ni < 2; ++ni) {
      int n = (nt << 7) + wid * 32 + ni * 16 + fi;
      float bv = HASBIAS ? bias[n] : 0.f;
#pragma unroll
      for (int r = 0; r < 4; ++r) {
        int m = m0 + mi * 16 + fq * 4 + r;
        float v = acc[mi][ni][r] + bv;
        if (ACT == 1) v = fmaxf(v, 0.f);
        if (ACT == 2) v = softplusf(v);
        out[(size_t)m * N + n] = v;
      }
    }
}

// ---------------- sum 32 partials + bias -> relu -> LayerNorm ----------------
__global__ __launch_bounds__(256) void ln32_k(const float* part_a, const float* part_b,
                                              const float* __restrict__ bias,
                                              const float* __restrict__ g,
                                              const float* __restrict__ bb,
                                              float* out) {
  int m = blockIdx.x, t = threadIdx.x;
  float s = bias[t];
  for (int z = 0; z < 16; ++z) s += part_a[((size_t)z * MROWS + m) * 256 + t];
  for (int z = 0; z < 16; ++z) s += part_b[((size_t)z * MROWS + m) * 256 + t];
  float v = fmaxf(s, 0.f);
  float sum = v, sq = v * v;
#pragma unroll
  for (int o = 1; o < 64; o <<= 1) { sum += __shfl_xor(sum, o); sq += __shfl_xor(sq, o); }
  __shared__ float s1[4], s2[4];
  int w = t >> 6;
  if ((t & 63) == 0) { s1[w] = sum; s2[w] = sq; }
  __syncthreads();
  sum = s1[0] + s1[1] + s1[2] + s1[3];
  sq  = s2[0] + s2[1] + s2[2] + s2[3];
  float mu  = sum * (1.f / 256.f);
  float var = sq * (1.f / 256.f) - mu * mu;
  out[(size_t)m * 256 + t] = (v - mu) * rsqrtf(var + 1e-5f) * g[t] + bb[t];
}

// ---------------- 1 partial + bias -> relu -> LN -> write skip AND xs=skip+pos ----------------
__global__ __launch_bounds__(256) void ln_pos_k(const float* __restrict__ part,
                                                const float* __restrict__ bias,
                                                const float* __restrict__ g,
                                                const float* __restrict__ bb,
                                                const float* __restrict__ pos,
                                                float* __restrict__ skip,
                                                float* __restrict__ xs) {
  int m = blockIdx.x, t = threadIdx.x;
  float s = bias[t] + part[(size_t)m * 256 + t];
  float v = fmaxf(s, 0.f);
  float sum = v, sq = v * v;
#pragma unroll
  for (int o = 1; o < 64; o <<= 1) { sum += __shfl_xor(sum, o); sq += __shfl_xor(sq, o); }
  __shared__ float s1[4], s2[4];
  int w = t >> 6;
  if ((t & 63) == 0) { s1[w] = sum; s2[w] = sq; }
  __syncthreads();
  sum = s1[0] + s1[1] + s1[2] + s1[3];
  sq  = s2[0] + s2[1] + s2[2] + s2[3];
  float mu  = sum * (1.f / 256.f);
  float var = sq * (1.f / 256.f) - mu * mu;
  float o2 = (v - mu) * rsqrtf(var + 1e-5f) * g[t] + bb[t];
  skip[(size_t)m * 256 + t] = o2;
  xs[(size_t)m * 256 + t] = o2 + pos[(m & 255) * 256 + t];
}

// ---------------- generic fp32 GEMM (kept for BC: N=64, K=512) ----------------
template <int RM, int ACT, int HASBIAS>
__global__ __launch_bounds__(256) void gemm_k(const float* __restrict__ A, int lda,
                                              const float* __restrict__ W,
                                              const float* __restrict__ bias,
                                              float* __restrict__ out,
                                              int M, int N, int K) {
  const int BM = RM * 16;
  __shared__ __align__(16) float As[16][RM * 16 + 4];
  __shared__ __align__(16) float Ws[16][68];
  int n0 = blockIdx.x << 6;
  int m0 = blockIdx.y * BM;
  int tid = threadIdx.x;
  int tx = tid & 15, ty = tid >> 4;
  float acc[RM][4];
#pragma unroll
  for (int r = 0; r < RM; ++r)
#pragma unroll
    for (int j = 0; j < 4; ++j) acc[r][j] = 0.f;

  for (int k0 = 0; k0 < K; k0 += 16) {
    __syncthreads();
    for (int i = tid; i < BM * 16; i += 256) {
      int r = i >> 4, kk = i & 15;
      As[kk][r] = A[(size_t)(m0 + r) * lda + k0 + kk];
    }
    for (int i = tid; i < 64 * 16; i += 256) {
      int r = i >> 4, kk = i & 15;
      int n = n0 + r;
      Ws[kk][r] = (n < N) ? W[(size_t)n * K + k0 + kk] : 0.f;
    }
    __syncthreads();
#pragma unroll
    for (int kk = 0; kk < 16; ++kk) {
      float4 wv = *(const float4*)&Ws[kk][tx << 2];
#pragma unroll
      for (int r = 0; r < RM; ++r) {
        float a = As[kk][ty * RM + r];
        acc[r][0] = fmaf(a, wv.x, acc[r][0]);
        acc[r][1] = fmaf(a, wv.y, acc[r][1]);
        acc[r][2] = fmaf(a, wv.z, acc[r][2]);
        acc[r][3] = fmaf(a, wv.w, acc[r][3]);
      }
    }
  }
#pragma unroll
  for (int r = 0; r < RM; ++r) {
    int m = m0 + ty * RM + r;
#pragma unroll
    for (int j = 0; j < 4; ++j) {
      int n = n0 + (tx << 2) + j;
      if (n < N) {
        float v = acc[r][j];
        if (HASBIAS) v += bias[n];
        if (ACT == 1) v = fmaxf(v, 0.f);
        if (ACT == 2) v = softplusf(v);
        out[(size_t)m * N + n] = v;
      }
    }
  }
}

// ---------------- causal depthwise conv1d(k=4) + silu ----------------
__global__ __launch_bounds__(256) void conv1d_silu_k(const float* __restrict__ xz,
                                                     const float* __restrict__ w,
                                                     const float* __restrict__ cb,
                                                     float* __restrict__ xc) {
  int i = blockIdx.x * 256 + threadIdx.x;  // over 2048*512
  int m = i >> 9, d = i & 511;
  int b = m >> 8, l = m & 255;
  float s = cb[d];
#pragma unroll
  for (int j = 0; j < 4; ++j) {
    int ll = l - 3 + j;
    if (ll >= 0) s = fmaf(w[(d << 2) + j], xz[((size_t)((b << 8) + ll) << 10) + d], s);
  }
  xc[(size_t)m * 512 + d] = siluf(s);
}

// ---------------- selective scan, windowed (16-step windows); BC buffer [2048][64] ----------------
__global__ __launch_bounds__(256, 1) void scan_k(const float* __restrict__ dt,
                                                 const float* __restrict__ u,
                                                 const float* __restrict__ bc,
                                                 const float* __restrict__ Alog,
                                                 const float* __restrict__ Dp,
                                                 const float* __restrict__ xz,
                                                 float* __restrict__ yg) {
  __shared__ float pbuf[4][2][16][33];
  int tid  = threadIdx.x;
  int widx = tid >> 6, lane = tid & 63;
  int wid  = (blockIdx.x << 2) + widx;
  int n = lane & 31, ch = lane >> 5;
  int d0 = (wid & 255) << 1;
  int d = d0 + ch;
  int b = wid >> 8;
  size_t base = (size_t)b << 8;
  float Av = -__expf(Alog[(d << 5) + n]);
  float Dv0 = Dp[d0], Dv1 = Dp[d0 + 1];
  float h = 0.f;
  int row = lane & 31;
  int rch = row >> 4, rlp = row & 15;
  int nh  = lane >> 5;
  int drow = d0 + rch;
  float Dsel = rch ? Dv1 : Dv0;

  for (int w0 = 0; w0 < 256; w0 += 16) {
    float dA[16], dBu[16], Cv[16];
#pragma unroll
    for (int j = 0; j < 16; ++j) {
      size_t r = base + w0 + j;
      float dtv = dt[(r << 9) + d];
      float uv  = u [(r << 9) + d];
      float Bv  = bc[(r << 6) + n];
      Cv[j]     = bc[(r << 6) + 32 + n];
      dA[j]  = __expf(dtv * Av);
      dBu[j] = dtv * Bv * uv;
    }
#pragma unroll
    for (int j = 0; j < 16; ++j) {
      h = fmaf(dA[j], h, dBu[j]);
      pbuf[widx][ch][j][n] = h * Cv[j];
    }
    __syncthreads();
    float s = 0.f;
#pragma unroll
    for (int nn = 0; nn < 16; ++nn) s += pbuf[widx][rch][rlp][(nh << 4) + nn];
    s += __shfl_xor(s, 32);
    if (lane < 32) {
      size_t r = base + w0 + rlp;
      float uv = u[(r << 9) + drow];
      float zv = xz[(r << 10) + 512 + drow];
      yg[(r << 9) + drow] = (s + uv * Dsel) * siluf(zv);
    }
    __syncthreads();
  }
}

// ---------------- direct 3x3 conv (IC=1), relu ----------------
template <int IC>
__global__ __launch_bounds__(256) void conv3x3_k(const float* __restrict__ in,
                                                 const float* __restrict__ w,
                                                 const float* __restrict__ bias,
                                                 float* __restrict__ out) {
  __shared__ float t[IC][6][68];
  __shared__ float wl[IC * 144];
  __shared__ float bl[16];
  int bid = blockIdx.x;
  int x0 = (bid & 3) << 6;
  int y0 = ((bid >> 2) & 63) << 2;
  int bb = bid >> 8;
  int tid = threadIdx.x;
  for (int i = tid; i < IC * 144; i += 256) {
    int oc = i & 15, t2 = i >> 4;
    wl[i] = w[(size_t)oc * (IC * 9) + t2];
  }
  if (tid < 16) bl[tid] = bias[tid];
  for (int i = tid; i < IC * 396; i += 256) {
    int ic = i / 396, rem = i - ic * 396;
    int r = rem / 66, cx = rem - r * 66;
    int y = y0 - 1 + r, xx = x0 - 1 + cx;
    float v = 0.f;
    if (y >= 0 && y < 256 && xx >= 0 && xx < 256)
      v = in[(((size_t)bb * IC + ic) << 16) + (y << 8) + xx];
    t[ic][r][cx] = v;
  }
  __syncthreads();
  int tx = tid & 15, row = (tid >> 4) & 3, ocq = tid >> 6;
  float acc[4][4];
#pragma unroll
  for (int o = 0; o < 4; ++o)
#pragma unroll
    for (int p = 0; p < 4; ++p) acc[o][p] = 0.f;

  for (int ic = 0; ic < IC; ++ic) {
#pragma unroll
    for (int dy = 0; dy < 3; ++dy) {
      const float* rp = &t[ic][row + dy][tx << 2];
      float rv[6];
#pragma unroll
      for (int q = 0; q < 6; ++q) rv[q] = rp[q];
#pragma unroll
      for (int dx = 0; dx < 3; ++dx) {
        const float* wp4 = &wl[(((ic * 3 + dy) * 3 + dx) << 4) + (ocq << 2)];
#pragma unroll
        for (int o = 0; o < 4; ++o) {
          float wv = wp4[o];
#pragma unroll
          for (int p = 0; p < 4; ++p) acc[o][p] = fmaf(rv[p + dx], wv, acc[o][p]);
        }
      }
    }
  }
  int xo = x0 + (tx << 2), yo = y0 + row;
#pragma unroll
  for (int o = 0; o < 4; ++o) {
    int oc = (ocq << 2) + o;
    float4 v4;
    v4.x = fmaxf(acc[o][0] + bl[oc], 0.f);
    v4.y = fmaxf(acc[o][1] + bl[oc], 0.f);
    v4.z = fmaxf(acc[o][2] + bl[oc], 0.f);
    v4.w = fmaxf(acc[o][3] + bl[oc], 0.f);
    *(float4*)&out[(((size_t)bb * 16 + oc) << 16) + (yo << 8) + xo] = v4;
  }
}

// ---------------- MFMA implicit-GEMM 3x3 conv, IC=OC=16, relu ----------------
__global__ __launch_bounds__(256, 2) void conv_mfma(const float* __restrict__ in,
                                                    const unsigned short* __restrict__ wth,
                                                    const unsigned short* __restrict__ wtl,
                                                    const float* __restrict__ bias,
                                                    float* __restrict__ out) {
  __shared__ __align__(16) char smem[58752];
  unsigned short* inh = (unsigned short*)smem;
  unsigned short* inl = inh + 14688;
  int bid = blockIdx.x;
  int txi = bid & 7;
  int tyi = (bid >> 3) & 15;
  int bb  = bid >> 7;
  int x0 = txi << 5, y0 = tyi << 4;
  int tid = threadIdx.x;

  for (int i = tid; i < 9792; i += 256) {
    int ic = i / 612, rem = i - ic * 612;
    int y = rem / 34, xx = rem - y * 34;
    int gy = y0 + y - 1, gx = x0 + xx - 1;
    float v = 0.f;
    if (gy >= 0 && gy < 256 && gx >= 0 && gx < 256)
      v = in[(((size_t)bb * 16 + ic) << 16) + (gy << 8) + gx];
    short hh, ll; split2(v, hh, ll);
    int a = (y * 34 + xx) * 24 + ic;
    inh[a] = (unsigned short)hh; inl[a] = (unsigned short)ll;
  }
  __syncthreads();

  int lane = tid & 63, w = tid >> 6;
  int fi = lane & 15, fq = lane >> 4;
  int fqh = fq >> 1, ich8 = (fq & 1) << 3;

  int adel[5];
#pragma unroll
  for (int s = 0; s < 5; ++s) {
    int dydx = 2 * s + fqh;
    if (dydx > 8) dydx = 8;
    int dy = dydx / 3, dx = dydx - dy * 3;
    adel[s] = (dy * 34 + dx) * 24;
  }
  int abase[8];
#pragma unroll
  for (int q = 0; q < 8; ++q) {
    int px = ((w * 8 + q) << 4) + fi;
    int y = px >> 5, xx = px & 31;
    abase[q] = (y * 34 + xx) * 24 + ich8;
  }
  short8v bh[5], bl[5];
#pragma unroll
  for (int s = 0; s < 5; ++s) {
    int slot = ((s * 4 + fq) * 16 + fi) * 8;
    bh[s] = *(const short8v*)(wth + slot);
    bl[s] = *(const short8v*)(wtl + slot);
  }

  f32x4 acc[8];
#pragma unroll
  for (int q = 0; q < 8; ++q) acc[q] = (f32x4)(0.f);

#pragma unroll
  for (int s = 0; s < 5; ++s) {
#pragma unroll
    for (int q = 0; q < 8; ++q) {
      short8v ah = *(const short8v*)&inh[abase[q] + adel[s]];
      short8v al = *(const short8v*)&inl[abase[q] + adel[s]];
      MFMA3(acc[q], ah, al, bh[s], bl[s]);
    }
  }
  __syncthreads();

  float* outs = (float*)smem;
#pragma unroll
  for (int q = 0; q < 8; ++q) {
    int pxb = ((w * 8 + q) << 4) + (fq << 2);
#pragma unroll
    for (int r = 0; r < 4; ++r)
      outs[fi * 514 + pxb + r] = acc[q][r];
  }
  __syncthreads();
  for (int i = tid; i < 8192; i += 256) {
    int oc = i >> 9, px = i & 511;
    int y = px >> 5, xx = px & 31;
    float v = fmaxf(outs[oc * 514 + px] + bias[oc], 0.f);
    out[(((size_t)bb * 16 + oc) << 16) + ((y0 + y) << 8) + x0 + xx] = v;
  }
}

// ---------------- 2x2 mean pool + 1x1 conv (16->1) ----------------
__global__ __launch_bounds__(256) void pool_c4_k(const float* __restrict__ in,
                                                 const float* __restrict__ w4,
                                                 const float* __restrict__ b4,
                                                 float* __restrict__ out) {
  int i = blockIdx.x * 256 + threadIdx.x;
  int x = i & 127, y = (i >> 7) & 127, b = i >> 14;
  float s = b4[0];
#pragma unroll
  for (int ic = 0; ic < 16; ++ic) {
    const float* p = in + (((size_t)b * 16 + ic) << 16) + ((size_t)(y << 1) << 8) + (x << 1);
    float m4 = 0.25f * (p[0] + p[1] + p[256] + p[257]);
    s = fmaf(w4[ic], m4, s);
  }
  out[i] = s;
}

// ---------------- launcher ----------------
extern "C" void kernel_launch(void* const* d_in, const int* in_sizes, int n_in,
                              void* d_out, int out_size, void* d_ws, size_t ws_size,
                              hipStream_t stream) {
  const float* x        = (const float*)d_in[0];
  const float* lin0_w   = (const float*)d_in[1];
  const float* lin0_b   = (const float*)d_in[2];
  const float* ln0_g    = (const float*)d_in[3];
  const float* ln0_bb   = (const float*)d_in[4];
  const float* lin1_w   = (const float*)d_in[5];
  const float* lin1_b   = (const float*)d_in[6];
  const float* ln1_g    = (const float*)d_in[7];
  const float* ln1_bb   = (const float*)d_in[8];
  const float* pos      = (const float*)d_in[9];
  const float* m_in_w   = (const float*)d_in[10];
  const float* m_conv_w = (const float*)d_in[11];
  const float* m_conv_b = (const float*)d_in[12];
  const float* m_xproj_w= (const float*)d_in[13];
  const float* m_dt_w   = (const float*)d_in[14];
  const float* m_dt_b   = (const float*)d_in[15];
  const float* m_Alog   = (const float*)d_in[16];
  const float* m_D      = (const float*)d_in[17];
  const float* m_out_w  = (const float*)d_in[18];
  const float* blk_w    = (const float*)d_in[19];
  const float* blk_b    = (const float*)d_in[20];
  const float* dec_w    = (const float*)d_in[21];
  const float* dec_b    = (const float*)d_in[22];
  const float* c1_w     = (const float*)d_in[23];
  const float* c1_b     = (const float*)d_in[24];
  const float* c2_w     = (const float*)d_in[25];
  const float* c2_b     = (const float*)d_in[26];
  const float* c3_w     = (const float*)d_in[27];
  const float* c3_b     = (const float*)d_in[28];
  const float* c4_w     = (const float*)d_in[29];
  const float* c4_b     = (const float*)d_in[30];

  float* ws  = (float*)d_ws;
  float* out = (float*)d_out;

  unsigned short* wt0h = (unsigned short*)(ws + F_WT0);
  unsigned short* wt0l = wt0h + 4194304;
  unsigned short* wmed = (unsigned short*)(ws + F_WMED);
  unsigned short* inw_h = wmed,           * inw_l = wmed + 262144;
  unsigned short* l1_h  = wmed + 524288,  * l1_l  = wmed + 589824;
  unsigned short* ow_h  = wmed + 655360,  * ow_l  = wmed + 786432;
  unsigned short* bk_h  = wmed + 917504,  * bk_l  = wmed + 983040;
  unsigned short* dc_h  = wmed + 1048576, * dc_l  = wmed + 1179648;
  unsigned short* wc2h  = wmed + 1310720, * wc2l  = wmed + 1313280;
  unsigned short* wc3h  = wmed + 1315840, * wc3l  = wmed + 1318400;
  unsigned short* wdth  = (unsigned short*)(ws + F_WDT);
  unsigned short* wdtl  = wdth + 262144;

  // 1. ALL weight tiling in one launch (964 blocks)
  tile_all<<<964, 256, 0, stream>>>(lin0_w, wt0h, wt0l, wmed,
                                    m_in_w, lin1_w, m_out_w, blk_w, dec_w,
                                    c2_w, c3_w, m_dt_w, m_xproj_w, wdth, wdtl);
  // 2. lin0 MFMA GEMM -> 32 partial slabs
  lin0_mfma<<<256, 512, 0, stream>>>(x, wt0h, wt0l, ws);
  // 3. reduce 32 + bias + relu + LN0 -> xt0
  ln32_k<<<MROWS, 256, 0, stream>>>(ws + F_PART, ws, lin0_b, ln0_g, ln0_bb, ws + F_XT0);
  // 4. lin1 -> part (raw)
  med_mfma<0, 0, 0><<<dim3(2, 32), 256, 0, stream>>>(ws + F_XT0, 256, nullptr, l1_h, l1_l,
                                                     nullptr, ws + F_PART, 256, 256);
  // 5. bias+relu+LN1 -> skip AND xs = skip+pos (fused)
  ln_pos_k<<<MROWS, 256, 0, stream>>>(ws + F_PART, lin1_b, ln1_g, ln1_bb, pos,
                                      ws + F_SKIP, ws + F_XS);
  // 6. xz = xs @ m_in_w^T  [2048,1024]
  med_mfma<0, 0, 0><<<dim3(8, 32), 256, 0, stream>>>(ws + F_XS, 256, nullptr, inw_h, inw_l,
                                                     nullptr, ws + F_XZ, 256, 1024);
  // 7. causal dwconv + silu -> xc
  conv1d_silu_k<<<4096, 256, 0, stream>>>(ws + F_XZ, m_conv_w, m_conv_b, ws + F_XC);
  // 8. BC = xc @ m_xproj_w[16:80]^T  [2048,64]
  gemm_k<2, 0, 0><<<dim3(1, 64), 256, 0, stream>>>(ws + F_XC, 512, m_xproj_w + 16 * 512,
                                                   nullptr, ws + F_XDBL, MROWS, 64, 512);
  // 9. dt = softplus(xc @ W'^T + m_dt_b)  [2048,512] (fused xproj[:16]+dt_w)
  med_mfma<2, 1, 0><<<dim3(4, 32), 256, 0, stream>>>(ws + F_XC, 512, nullptr, wdth, wdtl,
                                                     m_dt_b, ws + F_DT, 512, 512);
  // 10. selective scan + silu(z) gating -> yg
  scan_k<<<512, 256, 0, stream>>>(ws + F_DT, ws + F_XC, ws + F_XDBL, m_Alog, m_D,
                                  ws + F_XZ, ws + F_YG);
  // 11. ym = yg @ m_out_w^T
  med_mfma<0, 0, 0><<<dim3(2, 32), 256, 0, stream>>>(ws + F_YG, 512, nullptr, ow_h, ow_l,
                                                     nullptr, ws + F_YM, 512, 256);
  // 12. xs2 = ym @ blk_w^T + blk_b
  med_mfma<0, 1, 0><<<dim3(2, 32), 256, 0, stream>>>(ws + F_YM, 256, nullptr, bk_h, bk_l,
                                                     blk_b, ws + F_XS2, 256, 256);
  // 13. dec = relu([xs2|skip] @ dec_w^T + dec_b) (fused concat via two-source A)
  med_mfma<1, 1, 1><<<dim3(2, 32), 256, 0, stream>>>(ws + F_XS2, 256, ws + F_SKIP, dc_h, dc_l,
                                                     dec_b, ws + F_DEC, 512, 256);
  // 14. conv1 (IC=1, scalar)
  conv3x3_k<1><<<2048, 256, 0, stream>>>(ws + F_DEC, c1_w, c1_b, ws + F_C1);
  // 15-16. conv2/conv3 via MFMA implicit GEMM
  conv_mfma<<<1024, 256, 0, stream>>>(ws + F_C1, wc2h, wc2l, c2_b, ws + F_C2);
  conv_mfma<<<1024, 256, 0, stream>>>(ws + F_C2, wc3h, wc3l, c3_b, ws + F_C3);
  // 17. pool + 1x1 conv -> out
  pool_c4_k<<<512, 256, 0, stream>>>(ws + F_C3, c4_w, c4_b, out);
}

// Round 10
// 332.480 us; speedup vs baseline: 1.1400x; 1.1304x over previous
//
#include <hip/hip_runtime.h>
#include <hip/hip_bf16.h>
#include <cstddef>
#include <cstdint>

// ---------------- problem constants ----------------
#define MROWS 2048           // B8*L256
#define KBIG  16384          // DIN*CH32

typedef __attribute__((ext_vector_type(8))) short short8v;
typedef __attribute__((ext_vector_type(4))) float f32x4;
typedef unsigned int u32;

// ---------------- ws layout (float offsets) ----------------
static const size_t F_XT0  = 0;          // 2048*256
static const size_t F_SKIP = 524288;     // 2048*256
static const size_t F_XS   = 1048576;    // 2048*256
static const size_t F_XZ   = 1572864;    // 2048*1024
static const size_t F_XC   = 3670016;    // 2048*512
static const size_t F_XDBL = 4718592;    // 2048*64 (BC only)
static const size_t F_DT   = 4882432;    // 2048*512
static const size_t F_YG   = 5931008;    // 2048*512
static const size_t F_XS2  = 7503872;    // 2048*256
static const size_t F_DEC  = 9076736;    // 2048*256 (ends 9601024)
static const size_t F_WMED = 9700000;    // med W tiles + conv W tiles
static const size_t F_WT0  = 10485760;   // lin0 split-bf16 tiles (ends 14680064)
static const size_t F_PART = 14680064;   // lin0 partial slabs 0-15 (ends 23068672)
// lin0 partial slabs 16-31 live at float offset 0 (early chain region, free during lin0).
static const size_t F_WDT  = 23068672;   // dtbc tiles (327680 sh x2) + W2 tiles (131072 sh x2)
static const size_t F_C1   = 10485760;   // conv ping-pong (aliases WT0+PART, dead by then)
static const size_t F_C2   = 0;
static const size_t F_C3   = 14680064;

__device__ __forceinline__ float siluf(float v)     { return v / (1.f + __expf(-v)); }
__device__ __forceinline__ float softplusf(float v) { return v > 20.f ? v : log1pf(__expf(v)); }

__device__ __forceinline__ void split2(float v, short& h, short& l) {
  __hip_bfloat16 hb = __float2bfloat16(v);
  float hf = __bfloat162float(hb);
  __hip_bfloat16 lb = __float2bfloat16(v - hf);
  h = *(short*)&hb; l = *(short*)&lb;
}

__device__ __forceinline__ void glds16(const void* g, void* l) {
  __builtin_amdgcn_global_load_lds((const __attribute__((address_space(1))) u32*)g,
                                   (__attribute__((address_space(3))) u32*)l, 16, 0, 0);
}

#define MFMA3(acc, ah, al, bh, bl)                                            \
  acc = __builtin_amdgcn_mfma_f32_16x16x32_bf16(ah, bh, acc, 0, 0, 0);        \
  acc = __builtin_amdgcn_mfma_f32_16x16x32_bf16(al, bh, acc, 0, 0, 0);        \
  acc = __builtin_amdgcn_mfma_f32_16x16x32_bf16(ah, bl, acc, 0, 0, 0);

// ---------------- device helpers for weight tiling ----------------
__device__ __forceinline__ void med_tile_blk(const float* w, unsigned short* th,
                                             unsigned short* tl, int K, int nslots, int b) {
  int slot = b * 256 + threadIdx.x;
  if (slot >= nslots) return;
  int NS = K >> 5;
  int col = slot & 127, kg = (slot >> 7) & 3, rest = slot >> 9;
  int s = rest % NS, nt = rest / NS;
  const float* src = w + (size_t)(nt * 128 + col) * K + (s << 5) + (kg << 3);
  short8v h8, l8;
#pragma unroll
  for (int j = 0; j < 8; ++j) {
    short hh, ll; split2(src[j], hh, ll);
    h8[j] = hh; l8[j] = ll;
  }
  *(short8v*)(th + (size_t)slot * 8) = h8;
  *(short8v*)(tl + (size_t)slot * 8) = l8;
}

__device__ __forceinline__ void conv_tile_blk(const float* w, unsigned short* th,
                                              unsigned short* tl, int b) {
  int slot = b * 256 + threadIdx.x;   // 320 slots
  if (slot >= 320) return;
  int oc = slot & 15;
  int sfq = slot >> 4;
  int s = sfq >> 2, fq = sfq & 3;
  short8v h8, l8;
#pragma unroll
  for (int j = 0; j < 8; ++j) {
    int k = s * 32 + fq * 8 + j;
    float v = 0.f;
    if (k < 144) {
      int dydx = k >> 4, ic = k & 15;
      v = w[oc * 144 + ic * 9 + dydx];
    }
    short hh, ll; split2(v, hh, ll);
    h8[j] = hh; l8[j] = ll;
  }
  *(short8v*)(th + (size_t)slot * 8) = h8;
  *(short8v*)(tl + (size_t)slot * 8) = l8;
}

// dtbc fused weight: N=640, K=512. rows 0-511: W'=dt_w@xproj[:16]; 512-575: xproj[16:80]; else 0
__device__ __forceinline__ void wdtbc_tile_blk(const float* dtw, const float* xpw,
                                               unsigned short* th, unsigned short* tl, int b) {
  int slot = b * 256 + threadIdx.x;   // 40960 slots (160 blocks)
  int col = slot & 127, kg = (slot >> 7) & 3, rest = slot >> 9;
  int s = rest & 15, nt = rest >> 4;  // NS = 16
  int d = nt * 128 + col;
  short8v h8, l8;
  if (d < 512) {
    float wrow[16];
#pragma unroll
    for (int r = 0; r < 16; ++r) wrow[r] = dtw[d * 16 + r];
#pragma unroll
    for (int j = 0; j < 8; ++j) {
      int k = s * 32 + kg * 8 + j;
      float v = 0.f;
#pragma unroll
      for (int r = 0; r < 16; ++r) v = fmaf(wrow[r], xpw[r * 512 + k], v);
      short hh, ll; split2(v, hh, ll);
      h8[j] = hh; l8[j] = ll;
    }
  } else {
#pragma unroll
    for (int j = 0; j < 8; ++j) {
      int k = s * 32 + kg * 8 + j;
      float v = (d < 576) ? xpw[(size_t)(d - 512 + 16) * 512 + k] : 0.f;
      short hh, ll; split2(v, hh, ll);
      h8[j] = hh; l8[j] = ll;
    }
  }
  *(short8v*)(th + (size_t)slot * 8) = h8;
  *(short8v*)(tl + (size_t)slot * 8) = l8;
}

// W2 = blk_w @ m_out_w : [256][512]; tiled as med K=512 (16384 slots, 64 blocks)
__device__ __forceinline__ void w2_tile_blk(const float* bk, const float* ow,
                                            unsigned short* th, unsigned short* tl, int b) {
  int slot = b * 256 + threadIdx.x;
  int col = slot & 127, kg = (slot >> 7) & 3, rest = slot >> 9;
  int s = rest & 15, nt = rest >> 4;  // NS = 16
  int d = nt * 128 + col;
  int k0 = s * 32 + kg * 8;
  float acc[8];
#pragma unroll
  for (int j = 0; j < 8; ++j) acc[j] = 0.f;
  for (int r = 0; r < 256; ++r) {
    float bv = bk[(size_t)d * 256 + r];
    const float* op = ow + (size_t)r * 512 + k0;
#pragma unroll
    for (int j = 0; j < 8; ++j) acc[j] = fmaf(bv, op[j], acc[j]);
  }
  short8v h8, l8;
#pragma unroll
  for (int j = 0; j < 8; ++j) {
    short hh, ll; split2(acc[j], hh, ll);
    h8[j] = hh; l8[j] = ll;
  }
  *(short8v*)(th + (size_t)slot * 8) = h8;
  *(short8v*)(tl + (size_t)slot * 8) = l8;
}

// ---------------- mega weight-tiling kernel ----------------
__global__ __launch_bounds__(256) void tile_all(const float* __restrict__ lin0_w,
                                                unsigned short* __restrict__ wt0h,
                                                unsigned short* __restrict__ wt0l,
                                                unsigned short* __restrict__ wmed,
                                                const float* __restrict__ m_in_w,
                                                const float* __restrict__ lin1_w,
                                                const float* __restrict__ m_out_w,
                                                const float* __restrict__ blk_w,
                                                const float* __restrict__ dec_w,
                                                const float* __restrict__ c2_w,
                                                const float* __restrict__ c3_w,
                                                const float* __restrict__ m_dt_w,
                                                const float* __restrict__ m_xproj_w,
                                                unsigned short* __restrict__ wdth,
                                                unsigned short* __restrict__ wdtl,
                                                unsigned short* __restrict__ w2h,
                                                unsigned short* __restrict__ w2l) {
  __shared__ float ls[32 * 264];
  int b = blockIdx.x;
  int tid = threadIdx.x;
  if (b < 512) {
    int ct = b >> 6, kt = b & 63;
    int c0 = ct << 5, k0 = kt << 8;
    for (int u = tid; u < 2048; u += 256) {
      int col_l = u >> 6, f4i = u & 63;
      int k_l = f4i << 2;
      float4 v = *(const float4*)(lin0_w + (size_t)(c0 + col_l) * KBIG + k0 + k_l);
      float vv[4] = {v.x, v.y, v.z, v.w};
#pragma unroll
      for (int j = 0; j < 4; ++j) {
        int idx = k_l + j;
        ls[col_l * 264 + idx + (idx >> 5)] = vv[j];
      }
    }
    __syncthreads();
    for (int oi = tid; oi < 1024; oi += 256) {
      int col_l = oi & 31, c = oi >> 5;
      short8v h8, l8;
#pragma unroll
      for (int j = 0; j < 8; ++j) {
        float v = ls[col_l * 264 + j * 33 + c];
        short hh, ll; split2(v, hh, ll);
        h8[j] = hh; l8[j] = ll;
      }
      size_t slot = ((size_t)(c * 64 + kt)) * 256 + c0 + col_l;
      *(short8v*)(wt0h + slot * 8) = h8;
      *(short8v*)(wt0l + slot * 8) = l8;
    }
    return;
  }
  b -= 512;
  if (b < 128) { med_tile_blk(m_in_w,  wmed,           wmed + 262144,  256, 32768, b); return; }
  b -= 128;
  if (b < 32)  { med_tile_blk(lin1_w,  wmed + 524288,  wmed + 589824,  256, 8192,  b); return; }
  b -= 32;
  if (b < 64)  { med_tile_blk(dec_w,   wmed + 1048576, wmed + 1179648, 512, 16384, b); return; }
  b -= 64;
  if (b < 2)   { conv_tile_blk(c2_w, wmed + 1310720, wmed + 1313280, b); return; }
  b -= 2;
  if (b < 2)   { conv_tile_blk(c3_w, wmed + 1315840, wmed + 1318400, b); return; }
  b -= 2;
  if (b < 160) { wdtbc_tile_blk(m_dt_w, m_xproj_w, wdth, wdtl, b); return; }
  b -= 160;
  w2_tile_blk(blk_w, m_out_w, w2h, w2l, b);   // 64 blocks
}

// ---------------- lin0 MFMA GEMM: BM=256, BN=256(full), BK=32, split-K=32 ----------------
__global__ __launch_bounds__(512, 2) void lin0_mfma(const float* __restrict__ x,
                                                    const unsigned short* __restrict__ wh,
                                                    const unsigned short* __restrict__ wl,
                                                    float* __restrict__ wsbase) {
  __shared__ short8v Ad[2][2][1024];
  __shared__ short8v Bd[2][2][1024];
  int bid = blockIdx.x;
  int mt = bid >> 5, z = bid & 31;
  int tid = threadIdx.x;
  int lane = tid & 63, wid = tid >> 6;
  int wm = wid >> 2, wn = wid & 3;
  int fi = lane & 15, fq = lane >> 4;
  int arow = tid >> 1, kh = tid & 1;
  const float* xrow = x + (size_t)mt * 4194304 + (size_t)z * 131072 + (size_t)arow * 512;
  int skg = wid & 3, shl = wid >> 2;
  const unsigned short* wsrc = shl ? wl : wh;
  int aoff[8], boff[4];
#pragma unroll
  for (int mi = 0; mi < 8; ++mi) {
    int row = wm * 128 + mi * 16 + fi;
    aoff[mi] = fq * 256 + (row ^ (fq << 2));
  }
#pragma unroll
  for (int ni = 0; ni < 4; ++ni) boff[ni] = fq * 256 + wn * 64 + ni * 16 + fi;

  f32x4 acc[8][4];
#pragma unroll
  for (int mi = 0; mi < 8; ++mi)
#pragma unroll
    for (int ni = 0; ni < 4; ++ni) acc[mi][ni] = (f32x4)(0.f);

  {
    int slotbase = ((z * 16 + 0) * 4 + skg) * 256;
#pragma unroll
    for (int q = 0; q < 4; ++q)
      glds16(wsrc + (size_t)(slotbase + q * 64 + lane) * 8,
             (void*)&Bd[0][shl][skg * 256 + q * 64]);
    int f0 = kh << 4;
    float vv[16];
#pragma unroll
    for (int j4 = 0; j4 < 4; ++j4) {
      float4 v = *(const float4*)(xrow + f0 + 4 * j4);
      vv[4 * j4] = v.x; vv[4 * j4 + 1] = v.y; vv[4 * j4 + 2] = v.z; vv[4 * j4 + 3] = v.w;
    }
#pragma unroll
    for (int jg = 0; jg < 2; ++jg) {
      short8v h8, l8;
#pragma unroll
      for (int j = 0; j < 8; ++j) { short hh, ll; split2(vv[jg * 8 + j], hh, ll); h8[j] = hh; l8[j] = ll; }
      int kg = (kh << 1) + jg;
      int idx = kg * 256 + (arow ^ (kg << 2));
      Ad[0][0][idx] = h8; Ad[0][1][idx] = l8;
    }
    __syncthreads();
  }

  for (int s = 0; s < 16; ++s) {
    int cb = s & 1, nb = cb ^ 1;
    bool more = s < 15;
    float vv[16];
    if (more) {
      int slotbase = ((z * 16 + s + 1) * 4 + skg) * 256;
#pragma unroll
      for (int q = 0; q < 4; ++q)
        glds16(wsrc + (size_t)(slotbase + q * 64 + lane) * 8,
               (void*)&Bd[nb][shl][skg * 256 + q * 64]);
      int f0 = ((s + 1) << 5) + (kh << 4);
#pragma unroll
      for (int j4 = 0; j4 < 4; ++j4) {
        float4 v = *(const float4*)(xrow + f0 + 4 * j4);
        vv[4 * j4] = v.x; vv[4 * j4 + 1] = v.y; vv[4 * j4 + 2] = v.z; vv[4 * j4 + 3] = v.w;
      }
    }
    short8v fah[8], fal[8];
#pragma unroll
    for (int mi = 0; mi < 8; ++mi) { fah[mi] = Ad[cb][0][aoff[mi]]; fal[mi] = Ad[cb][1][aoff[mi]]; }
#pragma unroll
    for (int ni = 0; ni < 4; ++ni) {
      short8v bh = Bd[cb][0][boff[ni]];
      short8v bl = Bd[cb][1][boff[ni]];
#pragma unroll
      for (int mi = 0; mi < 8; ++mi) { MFMA3(acc[mi][ni], fah[mi], fal[mi], bh, bl); }
    }
    if (more) {
#pragma unroll
      for (int jg = 0; jg < 2; ++jg) {
        short8v h8, l8;
#pragma unroll
        for (int j = 0; j < 8; ++j) { short hh, ll; split2(vv[jg * 8 + j], hh, ll); h8[j] = hh; l8[j] = ll; }
        int kg = (kh << 1) + jg;
        int idx = kg * 256 + (arow ^ (kg << 2));
        Ad[nb][0][idx] = h8; Ad[nb][1][idx] = l8;
      }
    }
    __syncthreads();
  }

  size_t slabbase = (z < 16) ? (F_PART + (size_t)z * 524288) : ((size_t)(z - 16) * 524288);
  float* po = wsbase + slabbase + (size_t)mt * 65536;
#pragma unroll
  for (int mi = 0; mi < 8; ++mi)
#pragma unroll
    for (int ni = 0; ni < 4; ++ni) {
      int mloc = wm * 128 + mi * 16 + fq * 4;
      int n = wn * 64 + ni * 16 + fi;
#pragma unroll
      for (int r = 0; r < 4; ++r)
        po[(size_t)(mloc + r) * 256 + n] = acc[mi][ni][r];
    }
}

// ---------------- medium MFMA GEMM: BM=64, BN=128, BK=32, A+B dbuf (1 barrier/step) ----------------
// SRC2: A k>=256 comes from A2 (concat fusion). DTBC: n<512 softplus+bias->out, 512<=n<576 raw->bc_out.
template <int ACT, int HASBIAS, int SRC2, int DTBC>
__global__ __launch_bounds__(256, 2) void med_mfma(const float* __restrict__ A, int lda,
                                                   const float* __restrict__ A2,
                                                   const unsigned short* __restrict__ wh,
                                                   const unsigned short* __restrict__ wl,
                                                   const float* __restrict__ bias,
                                                   float* __restrict__ out,
                                                   float* __restrict__ bc_out,
                                                   int K, int N) {
  __shared__ short8v Ahs[2][2][256];   // [buf][h/l][kg*64+row'] = 16KB
  __shared__ short8v Bd[2][2][512];    // 32KB
  int nt = blockIdx.x, mt = blockIdx.y;
  int NS = K >> 5;
  int tid = threadIdx.x;
  int lane = tid & 63, wid = tid >> 6;
  int fi = lane & 15, fq = lane >> 4;
  int arow = tid >> 2, akg = tid & 3;
  int awidx = akg * 64 + (arow ^ (akg << 2));
  int m0 = mt << 6;
  size_t wtbase = (size_t)nt * NS;
  int aoff[4], boff[2];
#pragma unroll
  for (int mi = 0; mi < 4; ++mi) {
    int row = mi * 16 + fi;
    aoff[mi] = fq * 64 + (row ^ (fq << 2));
  }
#pragma unroll
  for (int ni = 0; ni < 2; ++ni) boff[ni] = fq * 128 + wid * 32 + ni * 16 + fi;

  f32x4 acc[4][2];
#pragma unroll
  for (int mi = 0; mi < 4; ++mi)
#pragma unroll
    for (int ni = 0; ni < 2; ++ni) acc[mi][ni] = (f32x4)(0.f);

  // prologue: stage step 0 into buf 0
  {
#pragma unroll
    for (int p = 0; p < 2; ++p) {
      int q = (wid << 1) + p;
      size_t gb = wtbase * 8192 + (size_t)q * 1024 + (size_t)lane * 16;
      glds16((const char*)wh + gb, (char*)&Bd[0][0][0] + q * 1024);
      glds16((const char*)wl + gb, (char*)&Bd[0][1][0] + q * 1024);
    }
    const float* gp = A + (size_t)(m0 + arow) * lda + (akg << 3);
    float4 v0 = *(const float4*)gp, v1 = *(const float4*)(gp + 4);
    float vv[8] = {v0.x, v0.y, v0.z, v0.w, v1.x, v1.y, v1.z, v1.w};
    short8v h8, l8;
#pragma unroll
    for (int j = 0; j < 8; ++j) { short hh, ll; split2(vv[j], hh, ll); h8[j] = hh; l8[j] = ll; }
    Ahs[0][0][awidx] = h8; Ahs[0][1][awidx] = l8;
    __syncthreads();
  }

  for (int s = 0; s < NS; ++s) {
    int cb = s & 1, nb = cb ^ 1;
    bool more = (s + 1) < NS;
    float4 v0, v1;
    if (more) {
#pragma unroll
      for (int p = 0; p < 2; ++p) {
        int q = (wid << 1) + p;
        size_t gb = (wtbase + s + 1) * 8192 + (size_t)q * 1024 + (size_t)lane * 16;
        glds16((const char*)wh + gb, (char*)&Bd[nb][0][0] + q * 1024);
        glds16((const char*)wl + gb, (char*)&Bd[nb][1][0] + q * 1024);
      }
      int sk = (s + 1) << 5;
      const float* gp;
      if (SRC2 && sk >= 256)
        gp = A2 + (size_t)(m0 + arow) * 256 + (sk - 256) + (akg << 3);
      else
        gp = A + (size_t)(m0 + arow) * lda + sk + (akg << 3);
      v0 = *(const float4*)gp; v1 = *(const float4*)(gp + 4);
    }
    short8v fah[4], fal[4];
#pragma unroll
    for (int mi = 0; mi < 4; ++mi) { fah[mi] = Ahs[cb][0][aoff[mi]]; fal[mi] = Ahs[cb][1][aoff[mi]]; }
#pragma unroll
    for (int ni = 0; ni < 2; ++ni) {
      short8v bh = Bd[cb][0][boff[ni]];
      short8v bl = Bd[cb][1][boff[ni]];
#pragma unroll
      for (int mi = 0; mi < 4; ++mi) { MFMA3(acc[mi][ni], fah[mi], fal[mi], bh, bl); }
    }
    if (more) {
      float vv[8] = {v0.x, v0.y, v0.z, v0.w, v1.x, v1.y, v1.z, v1.w};
      short8v h8, l8;
#pragma unroll
      for (int j = 0; j < 8; ++j) { short hh, ll; split2(vv[j], hh, ll); h8[j] = hh; l8[j] = ll; }
      Ahs[nb][0][awidx] = h8; Ahs[nb][1][awidx] = l8;
    }
    __syncthreads();   // nb A-writes visible + B glds drained
  }

#pragma unroll
  for (int mi = 0; mi < 4; ++mi)
#pragma unroll
    for (int ni = 0; ni < 2; ++ni) {
      int n = (nt << 7) + wid * 32 + ni * 16 + fi;
#pragma unroll
      for (int r = 0; r < 4; ++r) {
        int m = m0 + mi * 16 + fq * 4 + r;
        float a = acc[mi][ni][r];
        if (DTBC) {
          if (n < 512) out[(size_t)m * 512 + n] = softplusf(a + bias[n]);
          else if (n < 576) bc_out[(size_t)m * 64 + (n - 512)] = a;
        } else {
          float v = a + (HASBIAS ? bias[n] : 0.f);
          if (ACT == 1) v = fmaxf(v, 0.f);
          out[(size_t)m * N + n] = v;
        }
      }
    }
}

// ---------------- sum 32 partials + bias -> relu -> LayerNorm ----------------
__global__ __launch_bounds__(256) void ln32_k(const float* part_a, const float* part_b,
                                              const float* __restrict__ bias,
                                              const float* __restrict__ g,
                                              const float* __restrict__ bb,
                                              float* out) {
  int m = blockIdx.x, t = threadIdx.x;
  float s = bias[t];
  for (int z = 0; z < 16; ++z) s += part_a[((size_t)z * MROWS + m) * 256 + t];
  for (int z = 0; z < 16; ++z) s += part_b[((size_t)z * MROWS + m) * 256 + t];
  float v = fmaxf(s, 0.f);
  float sum = v, sq = v * v;
#pragma unroll
  for (int o = 1; o < 64; o <<= 1) { sum += __shfl_xor(sum, o); sq += __shfl_xor(sq, o); }
  __shared__ float s1[4], s2[4];
  int w = t >> 6;
  if ((t & 63) == 0) { s1[w] = sum; s2[w] = sq; }
  __syncthreads();
  sum = s1[0] + s1[1] + s1[2] + s1[3];
  sq  = s2[0] + s2[1] + s2[2] + s2[3];
  float mu  = sum * (1.f / 256.f);
  float var = sq * (1.f / 256.f) - mu * mu;
  out[(size_t)m * 256 + t] = (v - mu) * rsqrtf(var + 1e-5f) * g[t] + bb[t];
}

// ---------------- 1 partial + bias -> relu -> LN -> skip AND xs=skip+pos ----------------
__global__ __launch_bounds__(256) void ln_pos_k(const float* __restrict__ part,
                                                const float* __restrict__ bias,
                                                const float* __restrict__ g,
                                                const float* __restrict__ bb,
                                                const float* __restrict__ pos,
                                                float* __restrict__ skip,
                                                float* __restrict__ xs) {
  int m = blockIdx.x, t = threadIdx.x;
  float s = bias[t] + part[(size_t)m * 256 + t];
  float v = fmaxf(s, 0.f);
  float sum = v, sq = v * v;
#pragma unroll
  for (int o = 1; o < 64; o <<= 1) { sum += __shfl_xor(sum, o); sq += __shfl_xor(sq, o); }
  __shared__ float s1[4], s2[4];
  int w = t >> 6;
  if ((t & 63) == 0) { s1[w] = sum; s2[w] = sq; }
  __syncthreads();
  sum = s1[0] + s1[1] + s1[2] + s1[3];
  sq  = s2[0] + s2[1] + s2[2] + s2[3];
  float mu  = sum * (1.f / 256.f);
  float var = sq * (1.f / 256.f) - mu * mu;
  float o2 = (v - mu) * rsqrtf(var + 1e-5f) * g[t] + bb[t];
  skip[(size_t)m * 256 + t] = o2;
  xs[(size_t)m * 256 + t] = o2 + pos[(m & 255) * 256 + t];
}

// ---------------- causal depthwise conv1d(k=4) + silu ----------------
__global__ __launch_bounds__(256) void conv1d_silu_k(const float* __restrict__ xz,
                                                     const float* __restrict__ w,
                                                     const float* __restrict__ cb,
                                                     float* __restrict__ xc) {
  int i = blockIdx.x * 256 + threadIdx.x;  // over 2048*512
  int m = i >> 9, d = i & 511;
  int b = m >> 8, l = m & 255;
  float s = cb[d];
#pragma unroll
  for (int j = 0; j < 4; ++j) {
    int ll = l - 3 + j;
    if (ll >= 0) s = fmaf(w[(d << 2) + j], xz[((size_t)((b << 8) + ll) << 10) + d], s);
  }
  xc[(size_t)m * 512 + d] = siluf(s);
}

// ---------------- selective scan (16-step windows); BC buffer [2048][64] ----------------
__global__ __launch_bounds__(256, 1) void scan_k(const float* __restrict__ dt,
                                                 const float* __restrict__ u,
                                                 const float* __restrict__ bc,
                                                 const float* __restrict__ Alog,
                                                 const float* __restrict__ Dp,
                                                 const float* __restrict__ xz,
                                                 float* __restrict__ yg) {
  __shared__ float pbuf[4][2][16][33];
  int tid  = threadIdx.x;
  int widx = tid >> 6, lane = tid & 63;
  int wid  = (blockIdx.x << 2) + widx;
  int n = lane & 31, ch = lane >> 5;
  int d0 = (wid & 255) << 1;
  int d = d0 + ch;
  int b = wid >> 8;
  size_t base = (size_t)b << 8;
  float Av = -__expf(Alog[(d << 5) + n]);
  float Dv0 = Dp[d0], Dv1 = Dp[d0 + 1];
  float h = 0.f;
  int row = lane & 31;
  int rch = row >> 4, rlp = row & 15;
  int nh  = lane >> 5;
  int drow = d0 + rch;
  float Dsel = rch ? Dv1 : Dv0;

  for (int w0 = 0; w0 < 256; w0 += 16) {
    float dA[16], dBu[16], Cv[16];
#pragma unroll
    for (int j = 0; j < 16; ++j) {
      size_t r = base + w0 + j;
      float dtv = dt[(r << 9) + d];
      float uv  = u [(r << 9) + d];
      float Bv  = bc[(r << 6) + n];
      Cv[j]     = bc[(r << 6) + 32 + n];
      dA[j]  = __expf(dtv * Av);
      dBu[j] = dtv * Bv * uv;
    }
#pragma unroll
    for (int j = 0; j < 16; ++j) {
      h = fmaf(dA[j], h, dBu[j]);
      pbuf[widx][ch][j][n] = h * Cv[j];
    }
    __syncthreads();
    float s = 0.f;
#pragma unroll
    for (int nn = 0; nn < 16; ++nn) s += pbuf[widx][rch][rlp][(nh << 4) + nn];
    s += __shfl_xor(s, 32);
    if (lane < 32) {
      size_t r = base + w0 + rlp;
      float uv = u[(r << 9) + drow];
      float zv = xz[(r << 10) + 512 + drow];
      yg[(r << 9) + drow] = (s + uv * Dsel) * siluf(zv);
    }
    __syncthreads();
  }
}

// ---------------- direct 3x3 conv (IC=1), relu ----------------
template <int IC>
__global__ __launch_bounds__(256) void conv3x3_k(const float* __restrict__ in,
                                                 const float* __restrict__ w,
                                                 const float* __restrict__ bias,
                                                 float* __restrict__ out) {
  __shared__ float t[IC][6][68];
  __shared__ float wl[IC * 144];
  __shared__ float bl[16];
  int bid = blockIdx.x;
  int x0 = (bid & 3) << 6;
  int y0 = ((bid >> 2) & 63) << 2;
  int bb = bid >> 8;
  int tid = threadIdx.x;
  for (int i = tid; i < IC * 144; i += 256) {
    int oc = i & 15, t2 = i >> 4;
    wl[i] = w[(size_t)oc * (IC * 9) + t2];
  }
  if (tid < 16) bl[tid] = bias[tid];
  for (int i = tid; i < IC * 396; i += 256) {
    int ic = i / 396, rem = i - ic * 396;
    int r = rem / 66, cx = rem - r * 66;
    int y = y0 - 1 + r, xx = x0 - 1 + cx;
    float v = 0.f;
    if (y >= 0 && y < 256 && xx >= 0 && xx < 256)
      v = in[(((size_t)bb * IC + ic) << 16) + (y << 8) + xx];
    t[ic][r][cx] = v;
  }
  __syncthreads();
  int tx = tid & 15, row = (tid >> 4) & 3, ocq = tid >> 6;
  float acc[4][4];
#pragma unroll
  for (int o = 0; o < 4; ++o)
#pragma unroll
    for (int p = 0; p < 4; ++p) acc[o][p] = 0.f;

  for (int ic = 0; ic < IC; ++ic) {
#pragma unroll
    for (int dy = 0; dy < 3; ++dy) {
      const float* rp = &t[ic][row + dy][tx << 2];
      float rv[6];
#pragma unroll
      for (int q = 0; q < 6; ++q) rv[q] = rp[q];
#pragma unroll
      for (int dx = 0; dx < 3; ++dx) {
        const float* wp4 = &wl[(((ic * 3 + dy) * 3 + dx) << 4) + (ocq << 2)];
#pragma unroll
        for (int o = 0; o < 4; ++o) {
          float wv = wp4[o];
#pragma unroll
          for (int p = 0; p < 4; ++p) acc[o][p] = fmaf(rv[p + dx], wv, acc[o][p]);
        }
      }
    }
  }
  int xo = x0 + (tx << 2), yo = y0 + row;
#pragma unroll
  for (int o = 0; o < 4; ++o) {
    int oc = (ocq << 2) + o;
    float4 v4;
    v4.x = fmaxf(acc[o][0] + bl[oc], 0.f);
    v4.y = fmaxf(acc[o][1] + bl[oc], 0.f);
    v4.z = fmaxf(acc[o][2] + bl[oc], 0.f);
    v4.w = fmaxf(acc[o][3] + bl[oc], 0.f);
    *(float4*)&out[(((size_t)bb * 16 + oc) << 16) + (yo << 8) + xo] = v4;
  }
}

// ---------------- MFMA implicit-GEMM 3x3 conv, IC=OC=16, relu ----------------
__global__ __launch_bounds__(256, 2) void conv_mfma(const float* __restrict__ in,
                                                    const unsigned short* __restrict__ wth,
                                                    const unsigned short* __restrict__ wtl,
                                                    const float* __restrict__ bias,
                                                    float* __restrict__ out) {
  __shared__ __align__(16) char smem[58752];
  unsigned short* inh = (unsigned short*)smem;
  unsigned short* inl = inh + 14688;
  int bid = blockIdx.x;
  int txi = bid & 7;
  int tyi = (bid >> 3) & 15;
  int bb  = bid >> 7;
  int x0 = txi << 5, y0 = tyi << 4;
  int tid = threadIdx.x;

  for (int i = tid; i < 9792; i += 256) {
    int ic = i / 612, rem = i - ic * 612;
    int y = rem / 34, xx = rem - y * 34;
    int gy = y0 + y - 1, gx = x0 + xx - 1;
    float v = 0.f;
    if (gy >= 0 && gy < 256 && gx >= 0 && gx < 256)
      v = in[(((size_t)bb * 16 + ic) << 16) + (gy << 8) + gx];
    short hh, ll; split2(v, hh, ll);
    int a = (y * 34 + xx) * 24 + ic;
    inh[a] = (unsigned short)hh; inl[a] = (unsigned short)ll;
  }
  __syncthreads();

  int lane = tid & 63, w = tid >> 6;
  int fi = lane & 15, fq = lane >> 4;
  int fqh = fq >> 1, ich8 = (fq & 1) << 3;

  int adel[5];
#pragma unroll
  for (int s = 0; s < 5; ++s) {
    int dydx = 2 * s + fqh;
    if (dydx > 8) dydx = 8;
    int dy = dydx / 3, dx = dydx - dy * 3;
    adel[s] = (dy * 34 + dx) * 24;
  }
  int abase[8];
#pragma unroll
  for (int q = 0; q < 8; ++q) {
    int px = ((w * 8 + q) << 4) + fi;
    int y = px >> 5, xx = px & 31;
    abase[q] = (y * 34 + xx) * 24 + ich8;
  }
  short8v bh[5], bl[5];
#pragma unroll
  for (int s = 0; s < 5; ++s) {
    int slot = ((s * 4 + fq) * 16 + fi) * 8;
    bh[s] = *(const short8v*)(wth + slot);
    bl[s] = *(const short8v*)(wtl + slot);
  }

  f32x4 acc[8];
#pragma unroll
  for (int q = 0; q < 8; ++q) acc[q] = (f32x4)(0.f);

#pragma unroll
  for (int s = 0; s < 5; ++s) {
#pragma unroll
    for (int q = 0; q < 8; ++q) {
      short8v ah = *(const short8v*)&inh[abase[q] + adel[s]];
      short8v al = *(const short8v*)&inl[abase[q] + adel[s]];
      MFMA3(acc[q], ah, al, bh[s], bl[s]);
    }
  }
  __syncthreads();

  float* outs = (float*)smem;
#pragma unroll
  for (int q = 0; q < 8; ++q) {
    int pxb = ((w * 8 + q) << 4) + (fq << 2);
#pragma unroll
    for (int r = 0; r < 4; ++r)
      outs[fi * 514 + pxb + r] = acc[q][r];
  }
  __syncthreads();
  for (int i = tid; i < 8192; i += 256) {
    int oc = i >> 9, px = i & 511;
    int y = px >> 5, xx = px & 31;
    float v = fmaxf(outs[oc * 514 + px] + bias[oc], 0.f);
    out[(((size_t)bb * 16 + oc) << 16) + ((y0 + y) << 8) + x0 + xx] = v;
  }
}

// ---------------- 2x2 mean pool + 1x1 conv (16->1) ----------------
__global__ __launch_bounds__(256) void pool_c4_k(const float* __restrict__ in,
                                                 const float* __restrict__ w4,
                                                 const float* __restrict__ b4,
                                                 float* __restrict__ out) {
  int i = blockIdx.x * 256 + threadIdx.x;
  int x = i & 127, y = (i >> 7) & 127, b = i >> 14;
  float s = b4[0];
#pragma unroll
  for (int ic = 0; ic < 16; ++ic) {
    const float* p = in + (((size_t)b * 16 + ic) << 16) + ((size_t)(y << 1) << 8) + (x << 1);
    float m4 = 0.25f * (p[0] + p[1] + p[256] + p[257]);
    s = fmaf(w4[ic], m4, s);
  }
  out[i] = s;
}

// ---------------- launcher ----------------
extern "C" void kernel_launch(void* const* d_in, const int* in_sizes, int n_in,
                              void* d_out, int out_size, void* d_ws, size_t ws_size,
                              hipStream_t stream) {
  const float* x        = (const float*)d_in[0];
  const float* lin0_w   = (const float*)d_in[1];
  const float* lin0_b   = (const float*)d_in[2];
  const float* ln0_g    = (const float*)d_in[3];
  const float* ln0_bb   = (const float*)d_in[4];
  const float* lin1_w   = (const float*)d_in[5];
  const float* lin1_b   = (const float*)d_in[6];
  const float* ln1_g    = (const float*)d_in[7];
  const float* ln1_bb   = (const float*)d_in[8];
  const float* pos      = (const float*)d_in[9];
  const float* m_in_w   = (const float*)d_in[10];
  const float* m_conv_w = (const float*)d_in[11];
  const float* m_conv_b = (const float*)d_in[12];
  const float* m_xproj_w= (const float*)d_in[13];
  const float* m_dt_w   = (const float*)d_in[14];
  const float* m_dt_b   = (const float*)d_in[15];
  const float* m_Alog   = (const float*)d_in[16];
  const float* m_D      = (const float*)d_in[17];
  const float* m_out_w  = (const float*)d_in[18];
  const float* blk_w    = (const float*)d_in[19];
  const float* blk_b    = (const float*)d_in[20];
  const float* dec_w    = (const float*)d_in[21];
  const float* dec_b    = (const float*)d_in[22];
  const float* c1_w     = (const float*)d_in[23];
  const float* c1_b     = (const float*)d_in[24];
  const float* c2_w     = (const float*)d_in[25];
  const float* c2_b     = (const float*)d_in[26];
  const float* c3_w     = (const float*)d_in[27];
  const float* c3_b     = (const float*)d_in[28];
  const float* c4_w     = (const float*)d_in[29];
  const float* c4_b     = (const float*)d_in[30];

  float* ws  = (float*)d_ws;
  float* out = (float*)d_out;

  unsigned short* wt0h = (unsigned short*)(ws + F_WT0);
  unsigned short* wt0l = wt0h + 4194304;
  unsigned short* wmed = (unsigned short*)(ws + F_WMED);
  unsigned short* inw_h = wmed,           * inw_l = wmed + 262144;
  unsigned short* l1_h  = wmed + 524288,  * l1_l  = wmed + 589824;
  unsigned short* dc_h  = wmed + 1048576, * dc_l  = wmed + 1179648;
  unsigned short* wc2h  = wmed + 1310720, * wc2l  = wmed + 1313280;
  unsigned short* wc3h  = wmed + 1315840, * wc3l  = wmed + 1318400;
  unsigned short* wdth  = (unsigned short*)(ws + F_WDT);
  unsigned short* wdtl  = wdth + 327680;
  unsigned short* w2h   = wdtl + 327680;
  unsigned short* w2l   = w2h + 131072;

  // 1. ALL weight tiling in one launch (964 blocks)
  tile_all<<<964, 256, 0, stream>>>(lin0_w, wt0h, wt0l, wmed,
                                    m_in_w, lin1_w, m_out_w, blk_w, dec_w,
                                    c2_w, c3_w, m_dt_w, m_xproj_w,
                                    wdth, wdtl, w2h, w2l);
  // 2. lin0 MFMA GEMM -> 32 partial slabs
  lin0_mfma<<<256, 512, 0, stream>>>(x, wt0h, wt0l, ws);
  // 3. reduce 32 + bias + relu + LN0 -> xt0
  ln32_k<<<MROWS, 256, 0, stream>>>(ws + F_PART, ws, lin0_b, ln0_g, ln0_bb, ws + F_XT0);
  // 4. lin1 -> part (raw)
  med_mfma<0, 0, 0, 0><<<dim3(2, 32), 256, 0, stream>>>(ws + F_XT0, 256, nullptr, l1_h, l1_l,
                                                        nullptr, ws + F_PART, nullptr, 256, 256);
  // 5. bias+relu+LN1 -> skip AND xs = skip+pos
  ln_pos_k<<<MROWS, 256, 0, stream>>>(ws + F_PART, lin1_b, ln1_g, ln1_bb, pos,
                                      ws + F_SKIP, ws + F_XS);
  // 6. xz = xs @ m_in_w^T  [2048,1024]
  med_mfma<0, 0, 0, 0><<<dim3(8, 32), 256, 0, stream>>>(ws + F_XS, 256, nullptr, inw_h, inw_l,
                                                        nullptr, ws + F_XZ, nullptr, 256, 1024);
  // 7. causal dwconv + silu -> xc
  conv1d_silu_k<<<4096, 256, 0, stream>>>(ws + F_XZ, m_conv_w, m_conv_b, ws + F_XC);
  // 8. fused dt+BC: [softplus(xc@W'^T + dt_b) -> dt] and [xc@xproj[16:80]^T -> BC]
  med_mfma<0, 1, 0, 1><<<dim3(5, 32), 256, 0, stream>>>(ws + F_XC, 512, nullptr, wdth, wdtl,
                                                        m_dt_b, ws + F_DT, ws + F_XDBL, 512, 512);
  // 9. selective scan + silu(z) gating -> yg
  scan_k<<<512, 256, 0, stream>>>(ws + F_DT, ws + F_XC, ws + F_XDBL, m_Alog, m_D,
                                  ws + F_XZ, ws + F_YG);
  // 10. xs2 = yg @ W2^T + blk_b  (folded ym/blk GEMMs; W2 = blk_w@m_out_w)
  med_mfma<0, 1, 0, 0><<<dim3(2, 32), 256, 0, stream>>>(ws + F_YG, 512, nullptr, w2h, w2l,
                                                        blk_b, ws + F_XS2, nullptr, 512, 256);
  // 11. dec = relu([xs2|skip] @ dec_w^T + dec_b)
  med_mfma<1, 1, 1, 0><<<dim3(2, 32), 256, 0, stream>>>(ws + F_XS2, 256, ws + F_SKIP, dc_h, dc_l,
                                                        dec_b, ws + F_DEC, nullptr, 512, 256);
  // 12. conv1 (IC=1, scalar)
  conv3x3_k<1><<<2048, 256, 0, stream>>>(ws + F_DEC, c1_w, c1_b, ws + F_C1);
  // 13-14. conv2/conv3 via MFMA implicit GEMM
  conv_mfma<<<1024, 256, 0, stream>>>(ws + F_C1, wc2h, wc2l, c2_b, ws + F_C2);
  conv_mfma<<<1024, 256, 0, stream>>>(ws + F_C2, wc3h, wc3l, c3_b, ws + F_C3);
  // 15. pool + 1x1 conv -> out
  pool_c4_k<<<512, 256, 0, stream>>>(ws + F_C3, c4_w, c4_b, out);
}